// Round 7
// baseline (842.109 us; speedup 1.0000x reference)
//
#include <hip/hip_runtime.h>
#include <hip/hip_bf16.h>
#include <cmath>

// Problem constants
#define BB 64
#define NN 512
#define NBS 8
#define EE 2048
#define HH 128
#define LL 3
#define KK 4
#define AF 82
#define BF 6
#define SLAB 4194304   // B*N*H floats

typedef __attribute__((ext_vector_type(8))) short bf16x8;
typedef __attribute__((ext_vector_type(4))) float f32x4;

__device__ __forceinline__ float gelu1(float x){ return 0.5f*x*(1.f+erff(x*0.7071067811865475f)); }
__device__ __forceinline__ float sig1(float x){ return 1.f/(1.f+expf(-x)); }
__device__ __forceinline__ short f2bs(float x){ __hip_bfloat16 b=__float2bfloat16(x); return *reinterpret_cast<short*>(&b); }
__device__ __forceinline__ float bs2f(short s){ unsigned u = ((unsigned)(unsigned short)s) << 16; union{unsigned u; float f;} c; c.u=u; return c.f; }
__device__ __forceinline__ void split2(float v, short& hi, short& lo){ hi = f2bs(v); lo = f2bs(v - bs2f(hi)); }

#define MFMA3(ACC, AH, AL, BH, BL) \
    ACC = __builtin_amdgcn_mfma_f32_16x16x32_bf16(AH, BH, ACC, 0,0,0); \
    ACC = __builtin_amdgcn_mfma_f32_16x16x32_bf16(AL, BH, ACC, 0,0,0); \
    ACC = __builtin_amdgcn_mfma_f32_16x16x32_bf16(AH, BL, ACC, 0,0,0);

// ---------------------------------------------------------------------------
// k1 fat: pvf dense GEMM (blocks 0..255) || mvscore (blocks 256..1279)
// ---------------------------------------------------------------------------
__global__ __launch_bounds__(256) void layer_k1(
    const short* __restrict__ vfh, const short* __restrict__ vfl,
    const short* __restrict__ wtpv, short* __restrict__ pvfb,
    const short* __restrict__ wtwvm, const float* __restrict__ wvmb,
    const float* __restrict__ master,
    const float* __restrict__ wbw, const float* __restrict__ wbb,
    float* __restrict__ score)
{
    const int bid = blockIdx.x;
    const int t = threadIdx.x;
    const int lane = t & 63, wv = t >> 6;
    const int quad = lane >> 4, ml = lane & 15;

    if (bid < 256) {
        // ---------------- pvf ----------------
        const int m0 = bid*128 + wv*32;
        const int r0 = m0 + ml, r1 = r0 + 16;

        bf16x8 a0h[4], a0l[4], a1h[4], a1l[4];
        #pragma unroll
        for (int kc = 0; kc < 4; ++kc) {
            const int kq = kc*32 + quad*8;
            a0h[kc] = *(const bf16x8*)(vfh + (size_t)r0*128 + kq);
            a0l[kc] = *(const bf16x8*)(vfl + (size_t)r0*128 + kq);
            a1h[kc] = *(const bf16x8*)(vfh + (size_t)r1*128 + kq);
            a1l[kc] = *(const bf16x8*)(vfl + (size_t)r1*128 + kq);
        }
        f32x4 acc[16];
        #pragma unroll
        for (int i = 0; i < 16; ++i) acc[i] = (f32x4){0.f,0.f,0.f,0.f};
        const short* wcol = wtpv + (size_t)ml*128;
        #pragma unroll
        for (int kc = 0; kc < 4; ++kc) {
            const int kq = kc*32 + quad*8;
            #pragma unroll
            for (int nt = 0; nt < 8; ++nt) {
                const short* bp = wcol + (size_t)nt*16*128 + kq;
                bf16x8 bh = *(const bf16x8*)bp;
                bf16x8 bl = *(const bf16x8*)(bp + 49152);
                MFMA3(acc[nt],   a0h[kc], a0l[kc], bh, bl);
                MFMA3(acc[8+nt], a1h[kc], a1l[kc], bh, bl);
            }
        }
        #pragma unroll
        for (int mt = 0; mt < 2; ++mt)
            #pragma unroll
            for (int nt = 0; nt < 8; ++nt) {
                int col = nt*16 + ml;
                #pragma unroll
                for (int r = 0; r < 4; ++r) {
                    int gm = m0 + mt*16 + quad*4 + r;
                    pvfb[(size_t)gm*128 + col] = f2bs(acc[mt*8+nt][r]);
                }
            }
    } else {
        // ---------------- mvscore ----------------
        const int v = bid - 256;
        const int k = v >> 8;
        const int tile = v & 255;
        const int b = tile >> 2;
        const int r0 = tile*128 + wv*32 + ml;
        const int r1 = r0 + 16;

        bf16x8 a0h[4], a0l[4], a1h[4], a1l[4];
        #pragma unroll
        for (int kc = 0; kc < 4; ++kc) {
            const int kq = kc*32 + quad*8;
            a0h[kc] = *(const bf16x8*)(vfh + (size_t)r0*128 + kq);
            a0l[kc] = *(const bf16x8*)(vfl + (size_t)r0*128 + kq);
            a1h[kc] = *(const bf16x8*)(vfh + (size_t)r1*128 + kq);
            a1l[kc] = *(const bf16x8*)(vfl + (size_t)r1*128 + kq);
        }
        f32x4 acc[16];
        #pragma unroll
        for (int i = 0; i < 16; ++i) acc[i] = (f32x4){0.f,0.f,0.f,0.f};
        const short* wcol = wtwvm + (size_t)k*16384 + (size_t)ml*128;
        #pragma unroll
        for (int kc = 0; kc < 4; ++kc) {
            const int kq = kc*32 + quad*8;
            #pragma unroll
            for (int nt = 0; nt < 8; ++nt) {
                const short* bp = wcol + (size_t)nt*16*128 + kq;
                bf16x8 bh = *(const bf16x8*)bp;
                bf16x8 bl = *(const bf16x8*)(bp + 196608);
                MFMA3(acc[nt],   a0h[kc], a0l[kc], bh, bl);
                MFMA3(acc[8+nt], a1h[kc], a1l[kc], bh, bl);
            }
        }
        float wv8[8], bj8[8];
        #pragma unroll
        for (int nt = 0; nt < 8; ++nt) {
            int col = nt*16 + ml;
            wv8[nt] = master[(size_t)b*128 + col] * wbw[(size_t)k*128 + col];
            bj8[nt] = wvmb[(size_t)k*128 + col];
        }
        float kb = wbb[k];
        #pragma unroll
        for (int mt = 0; mt < 2; ++mt) {
            #pragma unroll
            for (int r = 0; r < 4; ++r) {
                float s = 0.f;
                #pragma unroll
                for (int nt = 0; nt < 8; ++nt)
                    s += tanhf(acc[mt*8+nt][r] + bj8[nt]) * wv8[nt];
                s += __shfl_xor(s, 1); s += __shfl_xor(s, 2);
                s += __shfl_xor(s, 4); s += __shfl_xor(s, 8);
                if (ml == 0) {
                    int nloc = (tile & 3)*128 + wv*32 + mt*16 + quad*4 + r;
                    score[((size_t)(b*KK + k))*NN + nloc] = s + kb;
                }
            }
        }
    }
}

// ---------------------------------------------------------------------------
// k2 fat: edge-sum (blocks 0..8191) || attctx (blocks 8192..8447)
// ---------------------------------------------------------------------------
__global__ __launch_bounds__(256) void layer_k2(
    const short* __restrict__ pvfb, const float* __restrict__ pet,
    const int* __restrict__ aadj, const int* __restrict__ badj,
    const int* __restrict__ edge, const float* __restrict__ nbm,
    short* __restrict__ nlh, short* __restrict__ nll,
    const float* __restrict__ score, const float* __restrict__ vm,
    const short* __restrict__ vfch, const short* __restrict__ vfcl,
    float* __restrict__ satt, float* __restrict__ ctx)
{
    __shared__ float smem[768];
    const int bid = blockIdx.x;
    const int t = threadIdx.x;

    if (bid < 8192) {
        const int w = t >> 6, l = t & 63;
        const int i = bid*4 + w;            // output row < 32768
        const int sg = l >> 4, j = l & 15;  // s-group, col-chunk (8 cols)
        float acc[8];
        #pragma unroll
        for (int c = 0; c < 8; ++c) acc[c] = 0.f;
        #pragma unroll
        for (int it = 0; it < 2; ++it) {
            int s = it*4 + sg;
            int flat = i*8 + s;
            int g = aadj[flat];
            int eid = edge[badj[flat]];
            float nv = nbm[flat];
            bf16x8 pv8 = *(const bf16x8*)(pvfb + (size_t)g*128 + j*8);
            const float* pp = pet + (size_t)eid*128 + j*8;
            float4 p0 = *(const float4*)pp, p1 = *(const float4*)(pp+4);
            float pe[8] = {p0.x,p0.y,p0.z,p0.w,p1.x,p1.y,p1.z,p1.w};
            #pragma unroll
            for (int c = 0; c < 8; ++c)
                acc[c] += gelu1(bs2f(pv8[c]) + pe[c]) * nv;
        }
        #pragma unroll
        for (int c = 0; c < 8; ++c) {
            acc[c] += __shfl_xor(acc[c], 16);
            acc[c] += __shfl_xor(acc[c], 32);
        }
        if (sg == 0) {
            short hs[8], ls[8];
            #pragma unroll
            for (int c = 0; c < 8; ++c) split2(acc[c], hs[c], ls[c]);
            size_t o = (size_t)i*128 + j*8;
            *(short4*)(nlh + o)     = make_short4(hs[0],hs[1],hs[2],hs[3]);
            *(short4*)(nlh + o + 4) = make_short4(hs[4],hs[5],hs[6],hs[7]);
            *(short4*)(nll + o)     = make_short4(ls[0],ls[1],ls[2],ls[3]);
            *(short4*)(nll + o + 4) = make_short4(ls[4],ls[5],ls[6],ls[7]);
        }
    } else {
        // ---------------- attctx ----------------
        float* red = smem;        // 256
        float* att = smem + 256;  // 512
        const int bk = bid - 8192, b = bk >> 2;
        float v0 = score[(size_t)bk*NN + t], v1 = score[(size_t)bk*NN + 256 + t];
        red[t] = fmaxf(v0, v1); __syncthreads();
        for (int s = 128; s; s >>= 1) { if (t < s) red[t] = fmaxf(red[t], red[t+s]); __syncthreads(); }
        float mx = red[0]; __syncthreads();
        float e0 = expf(v0 - mx) * vm[b*NN + t];
        float e1 = expf(v1 - mx) * vm[b*NN + t + 256];
        red[t] = e0 + e1; __syncthreads();
        for (int s = 128; s; s >>= 1) { if (t < s) red[t] += red[t+s]; __syncthreads(); }
        float sum = red[0];
        float inv = 1.f / (sum + 1e-6f);
        att[t] = e0*inv; att[t+256] = e1*inv;
        if (t == 0) satt[bk] = sum*inv;
        __syncthreads();
        const int d = t & 127, h = t >> 7;
        float acc = 0.f;
        const short* Vh = vfch + (size_t)b*NN*HH;
        const short* Vl = vfcl + (size_t)b*NN*HH;
        #pragma unroll 8
        for (int n = h*256; n < h*256 + 256; ++n)
            acc += att[n]*(bs2f(Vh[(size_t)n*HH + d]) + bs2f(Vl[(size_t)n*HH + d]));
        red[t] = acc; __syncthreads();
        if (t < 128) ctx[(size_t)bk*HH + t] = red[t] + red[t+128];
    }
}

// ---------------------------------------------------------------------------
// k3 fat: master (blocks 0..63) || vchain (blocks 64..1087)
// vchain: 32 rows/block, 4 waves, 2 col-tiles/wave, BC merged, planes-only.
// Grid 4.25 blocks/CU with launch_bounds(256,2) so VGPR stays ~128 (R2's
// failure was the (256,4) VGPR crush, not the tile size).
// ---------------------------------------------------------------------------
__global__ __launch_bounds__(256, 2) void layer_k3(
    // vchain
    const short* __restrict__ nlh, const short* __restrict__ nll,
    const short* __restrict__ vfch, const short* __restrict__ vfcl,
    short* __restrict__ vfnh, short* __restrict__ vfnl,
    const short* __restrict__ h0b,
    const short* __restrict__ wu2, const float* __restrict__ u2b,
    const short* __restrict__ wfu, const float* __restrict__ fub,
    const short* __restrict__ wbc, const float* __restrict__ zmb2v,
    const short* __restrict__ wih, const short* __restrict__ whh,
    const float* __restrict__ bih, const float* __restrict__ bhh,
    const float* __restrict__ t2, const float* __restrict__ m2m,
    float theta,
    // master
    const float* __restrict__ ctx, const float* __restrict__ satt,
    float* __restrict__ master,
    const float* __restrict__ wmain_w, const float* __restrict__ wmain_b,
    const float* __restrict__ khead_w, const float* __restrict__ khead_b,
    const float* __restrict__ wmaster_w, const float* __restrict__ wmaster_b,
    const float* __restrict__ wzs1_w,  const float* __restrict__ wzs1_b,
    const float* __restrict__ wzs2_w,  const float* __restrict__ wzs2_b,
    const float* __restrict__ WTih, const float* __restrict__ WThh,
    const float* __restrict__ bihm, const float* __restrict__ bhhm,
    const float* __restrict__ wm2m_n_w, const float* __restrict__ wm2m_n_b,
    const float* __restrict__ wzm2_n_w, const float* __restrict__ wzm2_n_b,
    float* __restrict__ m2m_out, float* __restrict__ t2_out)
{
    __shared__ __align__(16) char smem_raw[17408];   // 2 planes x [32][136] shorts
    const int bid = blockIdx.x;
    const int t = threadIdx.x;

    if (bid >= 64) {
        // ---------------- vchain: 32 rows per block ----------------
        short* sh = (short*)smem_raw;
        short* sl = sh + 32*136;
        const int vb = bid - 64;
        const int lane = t & 63, wv = t >> 6;
        const int quad = lane >> 4, ml = lane & 15;
        const int base = vb * 32;
        const int bb = base >> 9;
        const int c0 = wv*32 + ml;
        const int c1 = c0 + 16;
        const int kq0 = quad*8;

        f32x4 acc[2][2];
        #pragma unroll
        for (int rt = 0; rt < 2; ++rt) {
            acc[rt][0] = (f32x4){0.f,0.f,0.f,0.f};
            acc[rt][1] = (f32x4){0.f,0.f,0.f,0.f};
        }

        // ---- stage A: hi = concat(nl, vf) @ u2 ; sup = 0.9*hi + 0.1*h0 ----
        #pragma unroll
        for (int kc = 0; kc < 4; ++kc) {
            const int kq = kc*32 + kq0;
            const short* bp0 = wu2 + (size_t)c0*256 + kq;
            const short* bp1 = wu2 + (size_t)c1*256 + kq;
            bf16x8 b0h = *(const bf16x8*)bp0, b0l = *(const bf16x8*)(bp0+98304);
            bf16x8 b1h = *(const bf16x8*)bp1, b1l = *(const bf16x8*)(bp1+98304);
            #pragma unroll
            for (int rt = 0; rt < 2; ++rt) {
                const size_t ar = (size_t)(base + rt*16 + ml);
                bf16x8 ah = *(const bf16x8*)(nlh + ar*128 + kq);
                bf16x8 al = *(const bf16x8*)(nll + ar*128 + kq);
                MFMA3(acc[rt][0], ah, al, b0h, b0l);
                MFMA3(acc[rt][1], ah, al, b1h, b1l);
            }
        }
        #pragma unroll
        for (int kc = 0; kc < 4; ++kc) {
            const int kq = kc*32 + kq0;
            const short* bp0 = wu2 + (size_t)c0*256 + 128 + kq;
            const short* bp1 = wu2 + (size_t)c1*256 + 128 + kq;
            bf16x8 b0h = *(const bf16x8*)bp0, b0l = *(const bf16x8*)(bp0+98304);
            bf16x8 b1h = *(const bf16x8*)bp1, b1l = *(const bf16x8*)(bp1+98304);
            #pragma unroll
            for (int rt = 0; rt < 2; ++rt) {
                const size_t ar = (size_t)(base + rt*16 + ml);
                bf16x8 ah = *(const bf16x8*)(vfch + ar*128 + kq);
                bf16x8 al = *(const bf16x8*)(vfcl + ar*128 + kq);
                MFMA3(acc[rt][0], ah, al, b0h, b0l);
                MFMA3(acc[rt][1], ah, al, b1h, b1l);
            }
        }
        f32x4 sup[2][2];
        {
            const float bj0 = u2b[c0], bj1 = u2b[c1];
            #pragma unroll
            for (int rt = 0; rt < 2; ++rt) {
                #pragma unroll
                for (int r = 0; r < 4; ++r) {
                    const size_t grow = (size_t)(base + rt*16 + quad*4 + r);
                    sup[rt][0][r] = 0.9f*(acc[rt][0][r]+bj0) + 0.1f*bs2f(h0b[grow*128 + c0]);
                    sup[rt][1][r] = 0.9f*(acc[rt][1][r]+bj1) + 0.1f*bs2f(h0b[grow*128 + c1]);
                    const int lrow = rt*16 + quad*4 + r;
                    short h_, l_;
                    split2(sup[rt][0][r], h_, l_); sh[lrow*136 + c0] = h_; sl[lrow*136 + c0] = l_;
                    split2(sup[rt][1][r], h_, l_); sh[lrow*136 + c1] = h_; sl[lrow*136 + c1] = l_;
                }
            }
        }
        __syncthreads();

        // ---- stage BC (merged) ----
        f32x4 accz[2][2];
        #pragma unroll
        for (int rt = 0; rt < 2; ++rt) {
            acc[rt][0] = (f32x4){0.f,0.f,0.f,0.f};
            acc[rt][1] = (f32x4){0.f,0.f,0.f,0.f};
            accz[rt][0] = (f32x4){0.f,0.f,0.f,0.f};
            accz[rt][1] = (f32x4){0.f,0.f,0.f,0.f};
        }
        #pragma unroll
        for (int kc = 0; kc < 4; ++kc) {
            const int kq = kc*32 + kq0;
            const short* bp0 = wfu + (size_t)c0*128 + kq;
            const short* bp1 = wfu + (size_t)c1*128 + kq;
            const short* zp0 = wbc + (size_t)c0*128 + kq;
            const short* zp1 = wbc + (size_t)c1*128 + kq;
            bf16x8 b0h = *(const bf16x8*)bp0, b0l = *(const bf16x8*)(bp0+49152);
            bf16x8 b1h = *(const bf16x8*)bp1, b1l = *(const bf16x8*)(bp1+49152);
            bf16x8 z0h = *(const bf16x8*)zp0, z0l = *(const bf16x8*)(zp0+49152);
            bf16x8 z1h = *(const bf16x8*)zp1, z1l = *(const bf16x8*)(zp1+49152);
            #pragma unroll
            for (int rt = 0; rt < 2; ++rt) {
                bf16x8 xh = *(const bf16x8*)&sh[(rt*16+ml)*136 + kq];
                bf16x8 xl = *(const bf16x8*)&sl[(rt*16+ml)*136 + kq];
                MFMA3(acc[rt][0], xh, xl, b0h, b0l);
                MFMA3(acc[rt][1], xh, xl, b1h, b1l);
                MFMA3(accz[rt][0], xh, xl, z0h, z0l);
                MFMA3(accz[rt][1], xh, xl, z1h, z1l);
            }
        }
        f32x4 hid[2][2];
        {
            const float bj0 = fub[c0], bj1 = fub[c1];
            const float zb0 = zmb2v[c0] + t2[(size_t)bb*128 + c0];
            const float zb1 = zmb2v[c1] + t2[(size_t)bb*128 + c1];
            const float m20 = m2m[(size_t)bb*128 + c0], m21 = m2m[(size_t)bb*128 + c1];
            #pragma unroll
            for (int rt = 0; rt < 2; ++rt) {
                #pragma unroll
                for (int r = 0; r < 4; ++r) {
                    float sv0 = theta*(acc[rt][0][r]+bj0) + (1.f-theta)*sup[rt][0][r];
                    float sv1 = theta*(acc[rt][1][r]+bj1) + (1.f-theta)*sup[rt][1][r];
                    float z0 = sig1(accz[rt][0][r] + zb0);
                    float z1 = sig1(accz[rt][1][r] + zb1);
                    hid[rt][0][r] = (1.f-z0)*sv0 + z0*m20;
                    hid[rt][1][r] = (1.f-z1)*sv1 + z1*m21;
                }
            }
        }
        __syncthreads();
        #pragma unroll
        for (int rt = 0; rt < 2; ++rt) {
            #pragma unroll
            for (int r = 0; r < 4; ++r) {
                const int lrow = rt*16 + quad*4 + r;
                short h_, l_;
                split2(hid[rt][0][r], h_, l_); sh[lrow*136 + c0] = h_; sl[lrow*136 + c0] = l_;
                split2(hid[rt][1][r], h_, l_); sh[lrow*136 + c1] = h_; sl[lrow*136 + c1] = l_;
            }
        }
        __syncthreads();

        // ---- stage D: GRU ----
        f32x4 gr[2][2], gi[2][2], gh[2][2];
        #pragma unroll
        for (int rt = 0; rt < 2; ++rt) {
            gr[rt][0] = (f32x4){0.f,0.f,0.f,0.f};
            gr[rt][1] = (f32x4){0.f,0.f,0.f,0.f};
        }
        #pragma unroll
        for (int kc = 0; kc < 4; ++kc) {
            const int kq = kc*32 + kq0;
            const short* pw0 = wih + (size_t)c0*128 + kq;
            const short* pw1 = wih + (size_t)c1*128 + kq;
            const short* pu0 = whh + (size_t)c0*128 + kq;
            const short* pu1 = whh + (size_t)c1*128 + kq;
            bf16x8 w0h=*(const bf16x8*)pw0, w0l=*(const bf16x8*)(pw0+49152);
            bf16x8 w1h=*(const bf16x8*)pw1, w1l=*(const bf16x8*)(pw1+49152);
            bf16x8 u0h=*(const bf16x8*)pu0, u0l=*(const bf16x8*)(pu0+49152);
            bf16x8 u1h=*(const bf16x8*)pu1, u1l=*(const bf16x8*)(pu1+49152);
            #pragma unroll
            for (int rt = 0; rt < 2; ++rt) {
                const size_t ar = (size_t)(base + rt*16 + ml);
                bf16x8 xh = *(const bf16x8*)&sh[(rt*16+ml)*136 + kq];
                bf16x8 xl = *(const bf16x8*)&sl[(rt*16+ml)*136 + kq];
                bf16x8 hh = *(const bf16x8*)(vfch + ar*128 + kq);
                bf16x8 hl = *(const bf16x8*)(vfcl + ar*128 + kq);
                MFMA3(gr[rt][0], xh, xl, w0h, w0l);
                MFMA3(gr[rt][0], hh, hl, u0h, u0l);
                MFMA3(gr[rt][1], xh, xl, w1h, w1l);
                MFMA3(gr[rt][1], hh, hl, u1h, u1l);
            }
        }
        {
            const float br0 = bih[c0] + bhh[c0], br1 = bih[c1] + bhh[c1];
            #pragma unroll
            for (int rt = 0; rt < 2; ++rt) {
                #pragma unroll
                for (int r = 0; r < 4; ++r) {
                    gr[rt][0][r] = sig1(gr[rt][0][r] + br0);
                    gr[rt][1][r] = sig1(gr[rt][1][r] + br1);
                }
            }
        }
        // gate n
        #pragma unroll
        for (int rt = 0; rt < 2; ++rt) {
            gi[rt][0] = (f32x4){0.f,0.f,0.f,0.f};
            gi[rt][1] = (f32x4){0.f,0.f,0.f,0.f};
            gh[rt][0] = (f32x4){0.f,0.f,0.f,0.f};
            gh[rt][1] = (f32x4){0.f,0.f,0.f,0.f};
        }
        #pragma unroll
        for (int kc = 0; kc < 4; ++kc) {
            const int kq = kc*32 + kq0;
            const short* pw0 = wih + (size_t)(256 + c0)*128 + kq;
            const short* pw1 = wih + (size_t)(256 + c1)*128 + kq;
            const short* pu0 = whh + (size_t)(256 + c0)*128 + kq;
            const short* pu1 = whh + (size_t)(256 + c1)*128 + kq;
            bf16x8 w0h=*(const bf16x8*)pw0, w0l=*(const bf16x8*)(pw0+49152);
            bf16x8 w1h=*(const bf16x8*)pw1, w1l=*(const bf16x8*)(pw1+49152);
            bf16x8 u0h=*(const bf16x8*)pu0, u0l=*(const bf16x8*)(pu0+49152);
            bf16x8 u1h=*(const bf16x8*)pu1, u1l=*(const bf16x8*)(pu1+49152);
            #pragma unroll
            for (int rt = 0; rt < 2; ++rt) {
                const size_t ar = (size_t)(base + rt*16 + ml);
                bf16x8 xh = *(const bf16x8*)&sh[(rt*16+ml)*136 + kq];
                bf16x8 xl = *(const bf16x8*)&sl[(rt*16+ml)*136 + kq];
                bf16x8 hh = *(const bf16x8*)(vfch + ar*128 + kq);
                bf16x8 hl = *(const bf16x8*)(vfcl + ar*128 + kq);
                MFMA3(gi[rt][0], xh, xl, w0h, w0l);
                MFMA3(gh[rt][0], hh, hl, u0h, u0l);
                MFMA3(gi[rt][1], xh, xl, w1h, w1l);
                MFMA3(gh[rt][1], hh, hl, u1h, u1l);
            }
        }
        {
            const float bn0 = bih[256+c0], bn1 = bih[256+c1];
            const float un0 = bhh[256+c0], un1 = bhh[256+c1];
            #pragma unroll
            for (int rt = 0; rt < 2; ++rt) {
                #pragma unroll
                for (int r = 0; r < 4; ++r) {
                    gi[rt][0][r] = tanhf(gi[rt][0][r] + bn0 + gr[rt][0][r]*(gh[rt][0][r] + un0));
                    gi[rt][1][r] = tanhf(gi[rt][1][r] + bn1 + gr[rt][1][r]*(gh[rt][1][r] + un1));
                }
            }
        }
        // gate z: combined, accumulate into gh (freed)
        #pragma unroll
        for (int rt = 0; rt < 2; ++rt) {
            gh[rt][0] = (f32x4){0.f,0.f,0.f,0.f};
            gh[rt][1] = (f32x4){0.f,0.f,0.f,0.f};
        }
        #pragma unroll
        for (int kc = 0; kc < 4; ++kc) {
            const int kq = kc*32 + kq0;
            const short* pw0 = wih + (size_t)(128 + c0)*128 + kq;
            const short* pw1 = wih + (size_t)(128 + c1)*128 + kq;
            const short* pu0 = whh + (size_t)(128 + c0)*128 + kq;
            const short* pu1 = whh + (size_t)(128 + c1)*128 + kq;
            bf16x8 w0h=*(const bf16x8*)pw0, w0l=*(const bf16x8*)(pw0+49152);
            bf16x8 w1h=*(const bf16x8*)pw1, w1l=*(const bf16x8*)(pw1+49152);
            bf16x8 u0h=*(const bf16x8*)pu0, u0l=*(const bf16x8*)(pu0+49152);
            bf16x8 u1h=*(const bf16x8*)pu1, u1l=*(const bf16x8*)(pu1+49152);
            #pragma unroll
            for (int rt = 0; rt < 2; ++rt) {
                const size_t ar = (size_t)(base + rt*16 + ml);
                bf16x8 xh = *(const bf16x8*)&sh[(rt*16+ml)*136 + kq];
                bf16x8 xl = *(const bf16x8*)&sl[(rt*16+ml)*136 + kq];
                bf16x8 hh = *(const bf16x8*)(vfch + ar*128 + kq);
                bf16x8 hl = *(const bf16x8*)(vfcl + ar*128 + kq);
                MFMA3(gh[rt][0], xh, xl, w0h, w0l);
                MFMA3(gh[rt][0], hh, hl, u0h, u0l);
                MFMA3(gh[rt][1], xh, xl, w1h, w1l);
                MFMA3(gh[rt][1], hh, hl, u1h, u1l);
            }
        }
        {
            const float bz0 = bih[128+c0] + bhh[128+c0];
            const float bz1 = bih[128+c1] + bhh[128+c1];
            #pragma unroll
            for (int rt = 0; rt < 2; ++rt) {
                #pragma unroll
                for (int r = 0; r < 4; ++r) {
                    const size_t grow = (size_t)(base + rt*16 + quad*4 + r);
                    const size_t off0 = grow*128 + c0, off1 = grow*128 + c1;
                    float z0 = sig1(gh[rt][0][r] + bz0);
                    float z1 = sig1(gh[rt][1][r] + bz1);
                    float hp0 = bs2f(vfch[off0]) + bs2f(vfcl[off0]);
                    float hp1 = bs2f(vfch[off1]) + bs2f(vfcl[off1]);
                    float o0 = (1.f-z0)*gi[rt][0][r] + z0*hp0;
                    float o1 = (1.f-z1)*gi[rt][1][r] + z1*hp1;
                    short h_, l_;
                    split2(o0, h_, l_); vfnh[off0] = h_; vfnl[off0] = l_;
                    split2(o1, h_, l_); vfnh[off1] = h_; vfnl[off1] = l_;
                }
            }
        }
    } else {
        // ---------------- master path (blocks 0..63, overlaps vchain) ------
        float* smemf = (float*)smem_raw;
        float* xs = smemf;            // 512
        float* ms = smemf + 512;      // 128
        float* msN = smemf + 640;     // 128
        float* v_mtm = smemf + 768;   // 128
        float* v_mself = smemf + 896; // 128
        float* v_m2m = smemf + 1024;  // 128
        float* v_t2 = smemf + 1152;   // 128
        float* v_ts1 = smemf + 1280;  // 128
        float* v_ts2 = smemf + 1408;  // 128
        float* v_hsup = smemf + 1536; // 128
        float* gi = smemf + 1664;     // 384
        float* gh2 = smemf + 2048;    // 384
        float* red = smemf + 2432;    // 256
        const int b = bid;

        if (t < 128) ms[t] = master[(size_t)b*128 + t];
        __syncthreads();

        const int c = t & 127, p = t >> 7;

        #pragma unroll
        for (int k = 0; k < 4; ++k) {
            const float* cx = ctx + ((size_t)b*KK + k)*128;
            const float* Wk = wmain_w + (size_t)k*16384;
            float s = 0.f;
            for (int d = p*64; d < p*64+64; ++d) s += cx[d]*Wk[(size_t)d*128 + c];
            red[t] = s; __syncthreads();
            if (t < 128) xs[k*128 + c] = red[c] + red[c+128] + satt[(size_t)b*KK + k]*wmain_b[k*128 + c];
            __syncthreads();
        }

        auto matvec = [&](const float* src, const float* __restrict__ W,
                          const float* __restrict__ bias, int K, float* out, int act) {
            int half = K >> 1;
            int k0 = p*half, k1 = k0 + half;
            float s = 0.f;
            for (int k = k0; k < k1; ++k) s += src[k]*W[(size_t)k*128 + c];
            red[t] = s; __syncthreads();
            if (t < 128) {
                float v = red[c] + red[c+128] + bias[c];
                if (act == 1) v = gelu1(v); else if (act == 2) v = tanhf(v);
                out[c] = v;
            }
            __syncthreads();
        };

        matvec(xs, khead_w, khead_b, 512, v_mtm, 2);
        matvec(ms, wmaster_w, wmaster_b, 128, v_mself, 1);
        matvec(v_mself, wzs1_w, wzs1_b, 128, v_ts1, 0);
        matvec(v_mtm, wzs2_w, wzs2_b, 128, v_ts2, 0);

        if (t < 128) {
            float z = sig1(v_ts1[t] + v_ts2[t]);
            v_hsup[t] = (1.f-z)*v_mself[t] + z*v_mtm[t];
        }
        __syncthreads();

        for (int j = t; j < 384; j += 256) {
            float a = 0.f, h2 = 0.f;
            for (int k = 0; k < 128; ++k) {
                a  += v_hsup[k]*WTih[(size_t)k*384 + j];
                h2 += ms[k]*WThh[(size_t)k*384 + j];
            }
            gi[j] = a + bihm[j];
            gh2[j] = h2 + bhhm[j];
        }
        __syncthreads();
        if (t < 128) {
            float r = sig1(gi[t] + gh2[t]);
            float z = sig1(gi[128+t] + gh2[128+t]);
            float n = tanhf(gi[256+t] + r*gh2[256+t]);
            float nm = (1.f-z)*n + z*ms[t];
            master[(size_t)b*128 + t] = nm;
            msN[t] = nm;
        }
        __syncthreads();

        matvec(msN, wm2m_n_w, wm2m_n_b, 128, v_m2m, 1);
        matvec(v_m2m, wzm2_n_w, wzm2_n_b, 128, v_t2, 0);
        if (t < 128) {
            m2m_out[(size_t)b*128 + t] = v_m2m[t];
            t2_out[(size_t)b*128 + t]  = v_t2[t];
        }
    }
}

// ---------------------------------------------------------------------------
// embed: vf = gelu((atomf[vertex]*vm)@emb + b); stores planes + bf16 h0 only
// ---------------------------------------------------------------------------
__global__ __launch_bounds__(256) void embed_kernel(
    const float* __restrict__ atomf, const int* __restrict__ vertex,
    const float* __restrict__ vmask,
    const short* __restrict__ WT, const float* __restrict__ bias,
    short* __restrict__ h0b,
    short* __restrict__ vfh, short* __restrict__ vfl)
{
    const int t = threadIdx.x;
    const int lane = t & 63, wv = t >> 6;
    const int quad = lane >> 4, ml = lane & 15;
    const int m0 = blockIdx.x*128 + wv*32;
    const int r0 = m0 + ml, r1 = m0 + 16 + ml;
    const int ga0 = vertex[r0], ga1 = vertex[r1];
    const float vm0 = vmask[r0], vm1 = vmask[r1];

    f32x4 acc[16];
    #pragma unroll
    for (int i = 0; i < 16; ++i) acc[i] = (f32x4){0.f,0.f,0.f,0.f};
    const short* wcol = WT + (size_t)ml*96;

    #pragma unroll
    for (int kc = 0; kc < 3; ++kc) {
        const int kq = kc*32 + quad*8;
        float av0[8], av1[8];
        const float* p0r = atomf + (size_t)ga0*AF + kq;
        const float* p1r = atomf + (size_t)ga1*AF + kq;
        #pragma unroll
        for (int j2 = 0; j2 < 4; ++j2) {
            int k = kq + 2*j2;
            if (k + 2 <= AF) {
                float2 v0 = *(const float2*)(p0r + 2*j2);
                float2 v1 = *(const float2*)(p1r + 2*j2);
                av0[2*j2]=v0.x*vm0; av0[2*j2+1]=v0.y*vm0;
                av1[2*j2]=v1.x*vm1; av1[2*j2+1]=v1.y*vm1;
            } else { av0[2*j2]=0.f; av0[2*j2+1]=0.f; av1[2*j2]=0.f; av1[2*j2+1]=0.f; }
        }
        bf16x8 a0h, a0l, a1h, a1l;
        #pragma unroll
        for (int j = 0; j < 8; ++j) {
            short h, l;
            split2(av0[j], h, l); a0h[j]=h; a0l[j]=l;
            split2(av1[j], h, l); a1h[j]=h; a1l[j]=l;
        }
        #pragma unroll
        for (int nt = 0; nt < 8; ++nt) {
            const short* bp = wcol + (size_t)nt*16*96 + kq;
            bf16x8 bh = *(const bf16x8*)bp;
            bf16x8 bl = *(const bf16x8*)(bp + 12288);
            MFMA3(acc[nt],   a0h, a0l, bh, bl);
            MFMA3(acc[8+nt], a1h, a1l, bh, bl);
        }
    }

    #pragma unroll
    for (int mt = 0; mt < 2; ++mt) {
        #pragma unroll
        for (int nt = 0; nt < 8; ++nt) {
            int col = nt*16 + ml;
            float bj = bias[col];
            #pragma unroll
            for (int r = 0; r < 4; ++r) {
                int gm = m0 + mt*16 + quad*4 + r;
                float v = gelu1(acc[mt*8+nt][r] + bj);
                size_t off = (size_t)gm*128 + col;
                short h_, l_; split2(v, h_, l_);
                vfh[off] = h_; vfl[off] = l_;
                h0b[off] = h_;
            }
        }
    }
}

// ---------------------------------------------------------------------------
// master_init_a: partial sums (512 blocks) -> atomicAdd into zeroed master
// master_init_b: m2m_0 / t2_0 from master (64 blocks)
// ---------------------------------------------------------------------------
__global__ __launch_bounds__(256) void master_init_a(
    const short* __restrict__ vfh, const short* __restrict__ vfl,
    const float* __restrict__ vm,
    float* __restrict__ master)
{
    __shared__ float red[256];
    const int bid = blockIdx.x;
    const int b = bid >> 3, sl = bid & 7;
    const int t = threadIdx.x;
    const int c = t & 127, half = t >> 7;
    float s = 0.f;
    for (int n = sl*64 + half; n < sl*64 + 64; n += 2) {
        size_t idx = ((size_t)b*NN + n)*HH + c;
        s += (bs2f(vfh[idx]) + bs2f(vfl[idx])) * vm[b*NN + n];
    }
    red[t] = s; __syncthreads();
    if (t < 128) atomicAdd(&master[(size_t)b*HH + c], red[c] + red[c+128]);
}

__global__ __launch_bounds__(256) void master_init_b(
    const float* __restrict__ master,
    const float* __restrict__ wm2m_w, const float* __restrict__ wm2m_b,
    const float* __restrict__ wzm2_w, const float* __restrict__ wzm2_b,
    float* __restrict__ m2m_out, float* __restrict__ t2_out)
{
    __shared__ float red[256], ms[128], v_m2m[128];
    const int b = blockIdx.x, t = threadIdx.x;
    if (t < 128) ms[t] = master[(size_t)b*HH + t];
    __syncthreads();
    const int c = t & 127, p = t >> 7;
    {
        float s2 = 0.f;
        for (int k = p*64; k < p*64+64; ++k) s2 += ms[k]*wm2m_w[(size_t)k*128 + c];
        red[t] = s2; __syncthreads();
        if (t < 128) { float v = gelu1(red[c] + red[c+128] + wm2m_b[c]); v_m2m[c] = v; m2m_out[(size_t)b*128 + c] = v; }
        __syncthreads();
    }
    {
        float s2 = 0.f;
        for (int k = p*64; k < p*64+64; ++k) s2 += v_m2m[k]*wzm2_w[(size_t)k*128 + c];
        red[t] = s2; __syncthreads();
        if (t < 128) t2_out[(size_t)b*128 + c] = red[c] + red[c+128] + wzm2_b[c];
    }
}

// ---------------------------------------------------------------------------
// weight prep: all converts/transposes + pet table + W_BC + zmb2 + master zero
// ---------------------------------------------------------------------------
__device__ __forceinline__ void cvt_t2(const float* __restrict__ src, short* __restrict__ dst,
                                       int i, int K, int Kpad, int total, int zrows)
{
    int z = i / (128*Kpad); int rem = i - z*128*Kpad;
    int col = rem / Kpad; int k = rem - col*Kpad;
    float v = (k < K) ? src[(size_t)z*zrows*128 + (size_t)k*128 + col] : 0.f;
    short h, l; split2(v, h, l);
    dst[i] = h; dst[total + i] = l;
}

__global__ void wprep_kernel(
    const float* __restrict__ emb_w, const float* __restrict__ wvm_w,
    const float* __restrict__ u1_w, const float* __restrict__ u1_b,
    const float* __restrict__ u2_w,
    const float* __restrict__ fu_w, const float* __restrict__ fu_bv,
    const float* __restrict__ wzm1_w, const float* __restrict__ wzm1_bv,
    const float* __restrict__ g_wih, const float* __restrict__ g_whh,
    const float* __restrict__ gm_wih, const float* __restrict__ gm_whh,
    const float* __restrict__ bondf,
    short* __restrict__ wt_emb, short* __restrict__ wt_wvm,
    short* __restrict__ wt_pv, short* __restrict__ wt_u2,
    short* __restrict__ wt_fu, short* __restrict__ wt_wzm1,
    short* __restrict__ wt_gih, short* __restrict__ wt_ghh,
    short* __restrict__ wt_wbc, float* __restrict__ zmb2,
    float* __restrict__ WTih_s, float* __restrict__ WThh_s,
    float* __restrict__ pet, float* __restrict__ master0)
{
    int i = blockIdx.x*256 + threadIdx.x;
    if (i < 12288) cvt_t2(emb_w, wt_emb, i, 82, 96, 12288, 82);
    else if (i < 208896) cvt_t2(wvm_w, wt_wvm, i-12288, 128, 128, 196608, 128);
    else if (i < 258048) cvt_t2(u1_w, wt_pv, i-208896, 128, 128, 49152, 134);
    else if (i < 356352) cvt_t2(u2_w, wt_u2, i-258048, 256, 256, 98304, 256);
    else if (i < 405504) cvt_t2(fu_w, wt_fu, i-356352, 128, 128, 49152, 128);
    else if (i < 454656) cvt_t2(wzm1_w, wt_wzm1, i-405504, 128, 128, 49152, 128);
    else if (i < 503808) { int j = i-454656; short h,l; split2(g_wih[j],h,l); wt_gih[j]=h; wt_gih[49152+j]=l; }
    else if (i < 552960) { int j = i-503808; short h,l; split2(g_whh[j],h,l); wt_ghh[j]=h; wt_ghh[49152+j]=l; }
    else if (i < 602112) { int o = i-552960; int k = o/384, j = o-k*384; WTih_s[o] = gm_wih[j*128 + k]; }
    else if (i < 651264) { int o = i-602112; int k = o/384, j = o-k*384; WThh_s[o] = gm_whh[j*128 + k]; }
    else if (i < 655104) {
        int o = i-651264;               // < 3*10*128
        int l = o / 1280; int rem = o - l*1280;
        int e = rem >> 7; int c = rem & 127;
        float acc = u1_b[l*128 + c];
        #pragma unroll
        for (int j = 0; j < 6; ++j)
            acc += bondf[e*6 + j] * u1_w[((size_t)l*134 + 128 + j)*128 + c];
        pet[o] = acc;
    }
    else if (i < 704256) {
        // W_BC[l][in=k][out=c] = theta*sum_j fu[l][k][j]*wzm1[l][j][c] + (1-theta)*wzm1[l][k][c]
        int o = i - 655104;             // l*16384 + k*128 + c
        int li = o >> 14; int rem = o & 16383;
        int k = rem >> 7; int c = rem & 127;
        float theta = logf(0.5f/(float)(li+1) + 1.f);
        const float* fu = fu_w + (size_t)li*16384 + (size_t)k*128;
        const float* wz = wzm1_w + (size_t)li*16384;
        float s = 0.f;
        for (int j = 0; j < 128; ++j) s += fu[j] * wz[(size_t)j*128 + c];
        s = theta*s + (1.f-theta)*wz[(size_t)k*128 + c];
        short h, lo; split2(s, h, lo);
        size_t d = (size_t)li*16384 + (size_t)c*128 + k;   // transposed [col][k]
        wt_wbc[d] = h; wt_wbc[49152 + d] = lo;
    }
    else if (i < 704640) {
        // zmb2[l][c] = wzm1_b[l][c] + theta*sum_j fu_b[l][j]*wzm1[l][j][c]
        int o = i - 704256; int li = o >> 7; int c = o & 127;
        float theta = logf(0.5f/(float)(li+1) + 1.f);
        float s = 0.f;
        for (int j = 0; j < 128; ++j)
            s += fu_bv[li*128 + j] * wzm1_w[(size_t)li*16384 + (size_t)j*128 + c];
        zmb2[o] = wzm1_bv[li*128 + c] + theta*s;
    }
    else if (i < 712832) {
        master0[i - 704640] = 0.f;      // zero master for atomic partial sums
    }
}

// copy_out: reconstruct fp32 vf from hi/lo planes + append master
__global__ void copy_out_kernel(const short* __restrict__ vfh, const short* __restrict__ vfl,
                                const float* __restrict__ master,
                                float* __restrict__ out)
{
    int i = blockIdx.x*256 + threadIdx.x;
    const int nvf4 = SLAB/4;
    if (i < nvf4) {
        short4 h4 = ((const short4*)vfh)[i];
        short4 l4 = ((const short4*)vfl)[i];
        float4 v;
        v.x = bs2f(h4.x) + bs2f(l4.x);
        v.y = bs2f(h4.y) + bs2f(l4.y);
        v.z = bs2f(h4.z) + bs2f(l4.z);
        v.w = bs2f(h4.w) + bs2f(l4.w);
        ((float4*)out)[i] = v;
    } else {
        ((float4*)out)[i] = ((const float4*)master)[i - nvf4];
    }
}

// ---------------------------------------------------------------------------
extern "C" void kernel_launch(void* const* d_in, const int* in_sizes, int n_in,
                              void* d_out, int out_size, void* d_ws, size_t ws_size,
                              hipStream_t stream)
{
    (void)in_sizes; (void)n_in; (void)out_size; (void)ws_size;
    const float* vmask = (const float*)d_in[1];
    const int*   vertex= (const int*)d_in[2];
    const int*   edge  = (const int*)d_in[3];
    const int*   aadj  = (const int*)d_in[4];
    const int*   badj  = (const int*)d_in[5];
    const float* nbm   = (const float*)d_in[6];
    const float* atomf = (const float*)d_in[7];
    const float* bondf = (const float*)d_in[8];
    const float* emb_w = (const float*)d_in[9];
    const float* emb_b = (const float*)d_in[10];
    const float* u1_w  = (const float*)d_in[11];
    const float* u1_b  = (const float*)d_in[12];
    const float* u2_w  = (const float*)d_in[13];
    const float* u2_b  = (const float*)d_in[14];
    const float* fu_w  = (const float*)d_in[15];
    const float* fu_b  = (const float*)d_in[16];
    const float* wvm_w = (const float*)d_in[17];
    const float* wvm_b = (const float*)d_in[18];
    const float* wmain_w=(const float*)d_in[19];
    const float* wmain_b=(const float*)d_in[20];
    const float* wbmm_w= (const float*)d_in[21];
    const float* wbmm_b= (const float*)d_in[22];
    const float* khead_w=(const float*)d_in[23];
    const float* khead_b=(const float*)d_in[24];
    const float* wmaster_w=(const float*)d_in[25];
    const float* wmaster_b=(const float*)d_in[26];
    const float* wm2m_w= (const float*)d_in[27];
    const float* wm2m_b= (const float*)d_in[28];
    const float* wzm1_w= (const float*)d_in[29];
    const float* wzm1_b= (const float*)d_in[30];
    const float* wzm2_w= (const float*)d_in[31];
    const float* wzm2_b= (const float*)d_in[32];
    const float* wzs1_w= (const float*)d_in[33];
    const float* wzs1_b= (const float*)d_in[34];
    const float* wzs2_w= (const float*)d_in[35];
    const float* wzs2_b= (const float*)d_in[36];
    const float* g_wih = (const float*)d_in[37];
    const float* g_whh = (const float*)d_in[38];
    const float* g_bih = (const float*)d_in[39];
    const float* g_bhh = (const float*)d_in[40];
    const float* gm_wih= (const float*)d_in[41];
    const float* gm_whh= (const float*)d_in[42];
    const float* gm_bih= (const float*)d_in[43];
    const float* gm_bhh= (const float*)d_in[44];

    float* ws     = (float*)d_ws;
    float* vfA    = ws;                     // (fp32 slabs now unused; layout kept)
    float* vfB    = vfA + SLAB;
    float* score  = vfB + SLAB;
    float* ctx    = score + BB*KK*NN;
    float* satt   = ctx + BB*KK*HH;
    float* master = satt + BB*KK;
    float* m2mA   = master + BB*HH;
    float* t2A    = m2mA + BB*HH;
    float* m2mB   = t2A + BB*HH;
    float* t2B    = m2mB + BB*HH;
    float* WTih_s = t2B + BB*HH;
    float* WThh_s = WTih_s + 128*384;
    float* pet    = WThh_s + 128*384;       // 3*10*128
    short* vfhA   = (short*)(pet + 3840);
    short* vflA   = vfhA + SLAB;
    short* vfhB   = vflA + SLAB;
    short* vflB   = vfhB + SLAB;
    short* nlh    = vflB + SLAB;
    short* nll    = nlh + SLAB;
    short* pvfb   = nll + SLAB;
    short* h0b    = pvfb + SLAB;
    short* wt_emb   = h0b + SLAB;
    short* wt_wvm   = wt_emb   + 2*12288;
    short* wt_pv    = wt_wvm   + 2*196608;
    short* wt_u2    = wt_pv    + 2*49152;
    short* wt_fu    = wt_u2    + 2*98304;
    short* wt_wzm1  = wt_fu    + 2*49152;
    short* wt_gih   = wt_wzm1  + 2*49152;
    short* wt_ghh   = wt_gih   + 2*49152;
    short* wt_wbc   = wt_ghh   + 2*49152;
    float* zmb2     = (float*)(wt_wbc + 2*49152);  // 3*128

    wprep_kernel<<<2785, 256, 0, stream>>>(
        emb_w, wvm_w, u1_w, u1_b, u2_w, fu_w, fu_b, wzm1_w, wzm1_b,
        g_wih, g_whh, gm_wih, gm_whh, bondf,
        wt_emb, wt_wvm, wt_pv, wt_u2, wt_fu, wt_wzm1, wt_gih, wt_ghh,
        wt_wbc, zmb2, WTih_s, WThh_s, pet, master);

    embed_kernel<<<256, 256, 0, stream>>>(atomf, vertex, vmask, wt_emb, emb_b,
                                          h0b, vfhA, vflA);

    master_init_a<<<512, 256, 0, stream>>>(vfhA, vflA, vmask, master);
    master_init_b<<<BB, 256, 0, stream>>>(master, wm2m_w, wm2m_b, wzm2_w, wzm2_b,
                                          m2mA, t2A);

    for (int i = 0; i < LL; ++i) {
        float theta = logf(0.5f/(float)(i+1) + 1.f);
        const bool even = (i % 2 == 0);
        short* vfch = even ? vfhA : vfhB;
        short* vfcl = even ? vflA : vflB;
        short* vfnh = even ? vfhB : vfhA;
        short* vfnl = even ? vflB : vflA;
        // t2/m2m double-buffer: read current, master path writes next
        float* m2mR = even ? m2mA : m2mB;
        float* t2R  = even ? t2A  : t2B;
        float* m2mW = even ? m2mB : m2mA;
        float* t2W  = even ? t2B  : t2A;
        int nx = (i+1 < LL) ? i+1 : i;

        layer_k1<<<1280, 256, 0, stream>>>(
            vfch, vfcl,
            wt_pv + (size_t)i*16384, pvfb,
            wt_wvm + (size_t)i*4*16384, wvm_b + (size_t)i*4*128,
            master, wbmm_w + (size_t)i*KK*HH, wbmm_b + (size_t)i*KK, score);

        layer_k2<<<8448, 256, 0, stream>>>(
            pvfb, pet + (size_t)i*1280,
            aadj, badj, edge, nbm, nlh, nll,
            score, vmask, vfch, vfcl, satt, ctx);

        layer_k3<<<1088, 256, 0, stream>>>(
            nlh, nll, vfch, vfcl, vfnh, vfnl, h0b,
            wt_u2 + (size_t)i*128*256, u2_b + i*HH,
            wt_fu + (size_t)i*16384, fu_b + i*HH,
            wt_wbc + (size_t)i*16384, zmb2 + i*HH,
            wt_gih, wt_ghh, g_bih, g_bhh,
            t2R, m2mR, theta,
            ctx, satt, master,
            wmain_w + (size_t)i*KK*HH*HH, wmain_b + (size_t)i*KK*HH,
            khead_w + (size_t)i*KK*HH*HH, khead_b + i*HH,
            wmaster_w + (size_t)i*HH*HH, wmaster_b + i*HH,
            wzs1_w + (size_t)i*HH*HH, wzs1_b + i*HH,
            wzs2_w + (size_t)i*HH*HH, wzs2_b + i*HH,
            WTih_s, WThh_s, gm_bih, gm_bhh,
            wm2m_w + (size_t)nx*HH*HH, wm2m_b + nx*HH,
            wzm2_w + (size_t)nx*HH*HH, wzm2_b + nx*HH,
            m2mW, t2W);
    }

    copy_out_kernel<<<(SLAB + BB*HH)/4/256, 256, 0, stream>>>(vfhB, vflB, master, (float*)d_out);
}

// Round 8
// 774.309 us; speedup vs baseline: 1.0876x; 1.0876x over previous
//
#include <hip/hip_runtime.h>
#include <hip/hip_bf16.h>
#include <cmath>

// Problem constants
#define BB 64
#define NN 512
#define NBS 8
#define EE 2048
#define HH 128
#define LL 3
#define KK 4
#define AF 82
#define BF 6
#define SLAB 4194304   // B*N*H floats

typedef __attribute__((ext_vector_type(8))) short bf16x8;
typedef __attribute__((ext_vector_type(4))) float f32x4;

__device__ __forceinline__ float gelu1(float x){ return 0.5f*x*(1.f+erff(x*0.7071067811865475f)); }
__device__ __forceinline__ float sig1(float x){ return 1.f/(1.f+expf(-x)); }
__device__ __forceinline__ short f2bs(float x){ __hip_bfloat16 b=__float2bfloat16(x); return *reinterpret_cast<short*>(&b); }
__device__ __forceinline__ float bs2f(short s){ unsigned u = ((unsigned)(unsigned short)s) << 16; union{unsigned u; float f;} c; c.u=u; return c.f; }
__device__ __forceinline__ void split2(float v, short& hi, short& lo){ hi = f2bs(v); lo = f2bs(v - bs2f(hi)); }

#define MFMA3(ACC, AH, AL, BH, BL) \
    ACC = __builtin_amdgcn_mfma_f32_16x16x32_bf16(AH, BH, ACC, 0,0,0); \
    ACC = __builtin_amdgcn_mfma_f32_16x16x32_bf16(AL, BH, ACC, 0,0,0); \
    ACC = __builtin_amdgcn_mfma_f32_16x16x32_bf16(AH, BL, ACC, 0,0,0);

// ---------------------------------------------------------------------------
// k1 fat: pvf dense GEMM (blocks 0..255) || mvscore (blocks 256..1279)
// kc loops rolled (#pragma unroll 1) to shrink I$ footprint.
// ---------------------------------------------------------------------------
__global__ __launch_bounds__(256) void layer_k1(
    const short* __restrict__ vfh, const short* __restrict__ vfl,
    const short* __restrict__ wtpv, short* __restrict__ pvfb,
    const short* __restrict__ wtwvm, const float* __restrict__ wvmb,
    const float* __restrict__ master,
    const float* __restrict__ wbw, const float* __restrict__ wbb,
    float* __restrict__ score)
{
    const int bid = blockIdx.x;
    const int t = threadIdx.x;
    const int lane = t & 63, wv = t >> 6;
    const int quad = lane >> 4, ml = lane & 15;

    if (bid < 256) {
        // ---------------- pvf ----------------
        const int m0 = bid*128 + wv*32;
        const int r0 = m0 + ml, r1 = r0 + 16;

        f32x4 acc[16];
        #pragma unroll
        for (int i = 0; i < 16; ++i) acc[i] = (f32x4){0.f,0.f,0.f,0.f};
        const short* wcol = wtpv + (size_t)ml*128;
        #pragma unroll 1
        for (int kc = 0; kc < 4; ++kc) {
            const int kq = kc*32 + quad*8;
            bf16x8 a0h = *(const bf16x8*)(vfh + (size_t)r0*128 + kq);
            bf16x8 a0l = *(const bf16x8*)(vfl + (size_t)r0*128 + kq);
            bf16x8 a1h = *(const bf16x8*)(vfh + (size_t)r1*128 + kq);
            bf16x8 a1l = *(const bf16x8*)(vfl + (size_t)r1*128 + kq);
            #pragma unroll
            for (int nt = 0; nt < 8; ++nt) {
                const short* bp = wcol + (size_t)nt*16*128 + kq;
                bf16x8 bh = *(const bf16x8*)bp;
                bf16x8 bl = *(const bf16x8*)(bp + 49152);
                MFMA3(acc[nt],   a0h, a0l, bh, bl);
                MFMA3(acc[8+nt], a1h, a1l, bh, bl);
            }
        }
        #pragma unroll
        for (int mt = 0; mt < 2; ++mt)
            #pragma unroll
            for (int nt = 0; nt < 8; ++nt) {
                int col = nt*16 + ml;
                #pragma unroll
                for (int r = 0; r < 4; ++r) {
                    int gm = m0 + mt*16 + quad*4 + r;
                    pvfb[(size_t)gm*128 + col] = f2bs(acc[mt*8+nt][r]);
                }
            }
    } else {
        // ---------------- mvscore ----------------
        const int v = bid - 256;
        const int k = v >> 8;
        const int tile = v & 255;
        const int b = tile >> 2;
        const int r0 = tile*128 + wv*32 + ml;
        const int r1 = r0 + 16;

        f32x4 acc[16];
        #pragma unroll
        for (int i = 0; i < 16; ++i) acc[i] = (f32x4){0.f,0.f,0.f,0.f};
        const short* wcol = wtwvm + (size_t)k*16384 + (size_t)ml*128;
        #pragma unroll 1
        for (int kc = 0; kc < 4; ++kc) {
            const int kq = kc*32 + quad*8;
            bf16x8 a0h = *(const bf16x8*)(vfh + (size_t)r0*128 + kq);
            bf16x8 a0l = *(const bf16x8*)(vfl + (size_t)r0*128 + kq);
            bf16x8 a1h = *(const bf16x8*)(vfh + (size_t)r1*128 + kq);
            bf16x8 a1l = *(const bf16x8*)(vfl + (size_t)r1*128 + kq);
            #pragma unroll
            for (int nt = 0; nt < 8; ++nt) {
                const short* bp = wcol + (size_t)nt*16*128 + kq;
                bf16x8 bh = *(const bf16x8*)bp;
                bf16x8 bl = *(const bf16x8*)(bp + 196608);
                MFMA3(acc[nt],   a0h, a0l, bh, bl);
                MFMA3(acc[8+nt], a1h, a1l, bh, bl);
            }
        }
        float wv8[8], bj8[8];
        #pragma unroll
        for (int nt = 0; nt < 8; ++nt) {
            int col = nt*16 + ml;
            wv8[nt] = master[(size_t)b*128 + col] * wbw[(size_t)k*128 + col];
            bj8[nt] = wvmb[(size_t)k*128 + col];
        }
        float kb = wbb[k];
        #pragma unroll
        for (int mt = 0; mt < 2; ++mt) {
            #pragma unroll
            for (int r = 0; r < 4; ++r) {
                float s = 0.f;
                #pragma unroll
                for (int nt = 0; nt < 8; ++nt)
                    s += tanhf(acc[mt*8+nt][r] + bj8[nt]) * wv8[nt];
                s += __shfl_xor(s, 1); s += __shfl_xor(s, 2);
                s += __shfl_xor(s, 4); s += __shfl_xor(s, 8);
                if (ml == 0) {
                    int nloc = (tile & 3)*128 + wv*32 + mt*16 + quad*4 + r;
                    score[((size_t)(b*KK + k))*NN + nloc] = s + kb;
                }
            }
        }
    }
}

// ---------------------------------------------------------------------------
// k2 fat: edge-sum (blocks 0..8191) || attctx (blocks 8192..8447)
// ---------------------------------------------------------------------------
__global__ __launch_bounds__(256) void layer_k2(
    const short* __restrict__ pvfb, const float* __restrict__ pet,
    const int* __restrict__ aadj, const int* __restrict__ badj,
    const int* __restrict__ edge, const float* __restrict__ nbm,
    short* __restrict__ nlh, short* __restrict__ nll,
    const float* __restrict__ score, const float* __restrict__ vm,
    const float* __restrict__ vfc,
    float* __restrict__ satt, float* __restrict__ ctx)
{
    __shared__ float smem[768];
    const int bid = blockIdx.x;
    const int t = threadIdx.x;

    if (bid < 8192) {
        const int w = t >> 6, l = t & 63;
        const int i = bid*4 + w;            // output row < 32768
        const int sg = l >> 4, j = l & 15;  // s-group, col-chunk (8 cols)
        float acc[8];
        #pragma unroll
        for (int c = 0; c < 8; ++c) acc[c] = 0.f;
        #pragma unroll
        for (int it = 0; it < 2; ++it) {
            int s = it*4 + sg;
            int flat = i*8 + s;
            int g = aadj[flat];
            int eid = edge[badj[flat]];
            float nv = nbm[flat];
            bf16x8 pv8 = *(const bf16x8*)(pvfb + (size_t)g*128 + j*8);
            const float* pp = pet + (size_t)eid*128 + j*8;
            float4 p0 = *(const float4*)pp, p1 = *(const float4*)(pp+4);
            float pe[8] = {p0.x,p0.y,p0.z,p0.w,p1.x,p1.y,p1.z,p1.w};
            #pragma unroll
            for (int c = 0; c < 8; ++c)
                acc[c] += gelu1(bs2f(pv8[c]) + pe[c]) * nv;
        }
        #pragma unroll
        for (int c = 0; c < 8; ++c) {
            acc[c] += __shfl_xor(acc[c], 16);
            acc[c] += __shfl_xor(acc[c], 32);
        }
        if (sg == 0) {
            short hs[8], ls[8];
            #pragma unroll
            for (int c = 0; c < 8; ++c) split2(acc[c], hs[c], ls[c]);
            size_t o = (size_t)i*128 + j*8;
            *(short4*)(nlh + o)     = make_short4(hs[0],hs[1],hs[2],hs[3]);
            *(short4*)(nlh + o + 4) = make_short4(hs[4],hs[5],hs[6],hs[7]);
            *(short4*)(nll + o)     = make_short4(ls[0],ls[1],ls[2],ls[3]);
            *(short4*)(nll + o + 4) = make_short4(ls[4],ls[5],ls[6],ls[7]);
        }
    } else {
        // ---------------- attctx ----------------
        float* red = smem;        // 256
        float* att = smem + 256;  // 512
        const int bk = bid - 8192, b = bk >> 2;
        float v0 = score[(size_t)bk*NN + t], v1 = score[(size_t)bk*NN + 256 + t];
        red[t] = fmaxf(v0, v1); __syncthreads();
        for (int s = 128; s; s >>= 1) { if (t < s) red[t] = fmaxf(red[t], red[t+s]); __syncthreads(); }
        float mx = red[0]; __syncthreads();
        float e0 = expf(v0 - mx) * vm[b*NN + t];
        float e1 = expf(v1 - mx) * vm[b*NN + t + 256];
        red[t] = e0 + e1; __syncthreads();
        for (int s = 128; s; s >>= 1) { if (t < s) red[t] += red[t+s]; __syncthreads(); }
        float sum = red[0];
        float inv = 1.f / (sum + 1e-6f);
        att[t] = e0*inv; att[t+256] = e1*inv;
        if (t == 0) satt[bk] = sum*inv;
        __syncthreads();
        const int d = t & 127, h = t >> 7;
        float acc = 0.f;
        const float* V = vfc + (size_t)b*NN*HH;
        #pragma unroll 8
        for (int n = h*256; n < h*256 + 256; ++n) acc += att[n]*V[(size_t)n*HH + d];
        red[t] = acc; __syncthreads();
        if (t < 128) ctx[(size_t)bk*HH + t] = red[t] + red[t+128];
    }
}

// ---------------------------------------------------------------------------
// k3 fat: master (blocks 0..63) || vchain (blocks 64..575)
// R4 structure (64 rows/block, 4 waves, 2 col-tiles/wave, BC merged).
// All kc loops rolled (#pragma unroll 1): shrinks vchain code ~25KB -> ~2KB
// to test/fix I$-thrash (suspected cause of the invariant 72% stall).
// ---------------------------------------------------------------------------
__global__ __launch_bounds__(256, 2) void layer_k3(
    // vchain
    const short* __restrict__ nlh, const short* __restrict__ nll,
    const float* __restrict__ vfc, const short* __restrict__ vfch, const short* __restrict__ vfcl,
    float* __restrict__ vfn, short* __restrict__ vfnh, short* __restrict__ vfnl,
    const short* __restrict__ h0b,
    const short* __restrict__ wu2, const float* __restrict__ u2b,
    const short* __restrict__ wfu, const float* __restrict__ fub,
    const short* __restrict__ wbc, const float* __restrict__ zmb2v,
    const short* __restrict__ wih, const short* __restrict__ whh,
    const float* __restrict__ bih, const float* __restrict__ bhh,
    const float* __restrict__ t2, const float* __restrict__ m2m,
    float theta,
    // master
    const float* __restrict__ ctx, const float* __restrict__ satt,
    float* __restrict__ master,
    const float* __restrict__ wmain_w, const float* __restrict__ wmain_b,
    const float* __restrict__ khead_w, const float* __restrict__ khead_b,
    const float* __restrict__ wmaster_w, const float* __restrict__ wmaster_b,
    const float* __restrict__ wzs1_w,  const float* __restrict__ wzs1_b,
    const float* __restrict__ wzs2_w,  const float* __restrict__ wzs2_b,
    const float* __restrict__ WTih, const float* __restrict__ WThh,
    const float* __restrict__ bihm, const float* __restrict__ bhhm,
    const float* __restrict__ wm2m_n_w, const float* __restrict__ wm2m_n_b,
    const float* __restrict__ wzm2_n_w, const float* __restrict__ wzm2_n_b,
    float* __restrict__ m2m_out, float* __restrict__ t2_out)
{
    __shared__ __align__(16) char smem_raw[34816];   // 2 planes x [64][136] shorts
    const int bid = blockIdx.x;
    const int t = threadIdx.x;

    if (bid >= 64) {
        // ---------------- vchain: 64 rows per block ----------------
        short* sh = (short*)smem_raw;
        short* sl = sh + 64*136;
        const int vb = bid - 64;
        const int lane = t & 63, wv = t >> 6;
        const int quad = lane >> 4, ml = lane & 15;
        const int base = vb * 64;
        const int bb = base >> 9;
        const int c0 = wv*32 + ml;
        const int c1 = c0 + 16;
        const int kq0 = quad*8;

        f32x4 acc[4][2];
        #pragma unroll
        for (int rt = 0; rt < 4; ++rt) {
            acc[rt][0] = (f32x4){0.f,0.f,0.f,0.f};
            acc[rt][1] = (f32x4){0.f,0.f,0.f,0.f};
        }

        // ---- stage A: hi = concat(nl, vf) @ u2 ; sup = 0.9*hi + 0.1*h0 ----
        #pragma unroll 1
        for (int kc = 0; kc < 4; ++kc) {
            const int kq = kc*32 + kq0;
            const short* bp0 = wu2 + (size_t)c0*256 + kq;
            const short* bp1 = wu2 + (size_t)c1*256 + kq;
            bf16x8 b0h = *(const bf16x8*)bp0, b0l = *(const bf16x8*)(bp0+98304);
            bf16x8 b1h = *(const bf16x8*)bp1, b1l = *(const bf16x8*)(bp1+98304);
            #pragma unroll
            for (int rt = 0; rt < 4; ++rt) {
                const size_t ar = (size_t)(base + rt*16 + ml);
                bf16x8 ah = *(const bf16x8*)(nlh + ar*128 + kq);
                bf16x8 al = *(const bf16x8*)(nll + ar*128 + kq);
                MFMA3(acc[rt][0], ah, al, b0h, b0l);
                MFMA3(acc[rt][1], ah, al, b1h, b1l);
            }
        }
        #pragma unroll 1
        for (int kc = 0; kc < 4; ++kc) {
            const int kq = kc*32 + kq0;
            const short* bp0 = wu2 + (size_t)c0*256 + 128 + kq;
            const short* bp1 = wu2 + (size_t)c1*256 + 128 + kq;
            bf16x8 b0h = *(const bf16x8*)bp0, b0l = *(const bf16x8*)(bp0+98304);
            bf16x8 b1h = *(const bf16x8*)bp1, b1l = *(const bf16x8*)(bp1+98304);
            #pragma unroll
            for (int rt = 0; rt < 4; ++rt) {
                const size_t ar = (size_t)(base + rt*16 + ml);
                bf16x8 ah = *(const bf16x8*)(vfch + ar*128 + kq);
                bf16x8 al = *(const bf16x8*)(vfcl + ar*128 + kq);
                MFMA3(acc[rt][0], ah, al, b0h, b0l);
                MFMA3(acc[rt][1], ah, al, b1h, b1l);
            }
        }
        f32x4 sup[4][2];
        {
            const float bj0 = u2b[c0], bj1 = u2b[c1];
            #pragma unroll
            for (int rt = 0; rt < 4; ++rt) {
                #pragma unroll
                for (int r = 0; r < 4; ++r) {
                    const size_t grow = (size_t)(base + rt*16 + quad*4 + r);
                    sup[rt][0][r] = 0.9f*(acc[rt][0][r]+bj0) + 0.1f*bs2f(h0b[grow*128 + c0]);
                    sup[rt][1][r] = 0.9f*(acc[rt][1][r]+bj1) + 0.1f*bs2f(h0b[grow*128 + c1]);
                    const int lrow = rt*16 + quad*4 + r;
                    short h_, l_;
                    split2(sup[rt][0][r], h_, l_); sh[lrow*136 + c0] = h_; sl[lrow*136 + c0] = l_;
                    split2(sup[rt][1][r], h_, l_); sh[lrow*136 + c1] = h_; sl[lrow*136 + c1] = l_;
                }
            }
        }
        __syncthreads();

        // ---- stage BC (merged): sv = theta*(sup@fu+b)+(1-theta)*sup ;
        //      z = sig(sup@W_BC + zmb2 + t2) ; hid = (1-z)*sv + z*m2m ----
        f32x4 accz[4][2];
        #pragma unroll
        for (int rt = 0; rt < 4; ++rt) {
            acc[rt][0] = (f32x4){0.f,0.f,0.f,0.f};
            acc[rt][1] = (f32x4){0.f,0.f,0.f,0.f};
            accz[rt][0] = (f32x4){0.f,0.f,0.f,0.f};
            accz[rt][1] = (f32x4){0.f,0.f,0.f,0.f};
        }
        #pragma unroll 1
        for (int kc = 0; kc < 4; ++kc) {
            const int kq = kc*32 + kq0;
            const short* bp0 = wfu + (size_t)c0*128 + kq;
            const short* bp1 = wfu + (size_t)c1*128 + kq;
            const short* zp0 = wbc + (size_t)c0*128 + kq;
            const short* zp1 = wbc + (size_t)c1*128 + kq;
            bf16x8 b0h = *(const bf16x8*)bp0, b0l = *(const bf16x8*)(bp0+49152);
            bf16x8 b1h = *(const bf16x8*)bp1, b1l = *(const bf16x8*)(bp1+49152);
            bf16x8 z0h = *(const bf16x8*)zp0, z0l = *(const bf16x8*)(zp0+49152);
            bf16x8 z1h = *(const bf16x8*)zp1, z1l = *(const bf16x8*)(zp1+49152);
            #pragma unroll
            for (int rt = 0; rt < 4; ++rt) {
                bf16x8 xh = *(const bf16x8*)&sh[(rt*16+ml)*136 + kq];
                bf16x8 xl = *(const bf16x8*)&sl[(rt*16+ml)*136 + kq];
                MFMA3(acc[rt][0], xh, xl, b0h, b0l);
                MFMA3(acc[rt][1], xh, xl, b1h, b1l);
                MFMA3(accz[rt][0], xh, xl, z0h, z0l);
                MFMA3(accz[rt][1], xh, xl, z1h, z1l);
            }
        }
        f32x4 hid[4][2];
        {
            const float bj0 = fub[c0], bj1 = fub[c1];
            const float zb0 = zmb2v[c0] + t2[(size_t)bb*128 + c0];
            const float zb1 = zmb2v[c1] + t2[(size_t)bb*128 + c1];
            const float m20 = m2m[(size_t)bb*128 + c0], m21 = m2m[(size_t)bb*128 + c1];
            #pragma unroll
            for (int rt = 0; rt < 4; ++rt) {
                #pragma unroll
                for (int r = 0; r < 4; ++r) {
                    float sv0 = theta*(acc[rt][0][r]+bj0) + (1.f-theta)*sup[rt][0][r];
                    float sv1 = theta*(acc[rt][1][r]+bj1) + (1.f-theta)*sup[rt][1][r];
                    float z0 = sig1(accz[rt][0][r] + zb0);
                    float z1 = sig1(accz[rt][1][r] + zb1);
                    hid[rt][0][r] = (1.f-z0)*sv0 + z0*m20;
                    hid[rt][1][r] = (1.f-z1)*sv1 + z1*m21;
                }
            }
        }
        __syncthreads();
        #pragma unroll
        for (int rt = 0; rt < 4; ++rt) {
            #pragma unroll
            for (int r = 0; r < 4; ++r) {
                const int lrow = rt*16 + quad*4 + r;
                short h_, l_;
                split2(hid[rt][0][r], h_, l_); sh[lrow*136 + c0] = h_; sl[lrow*136 + c0] = l_;
                split2(hid[rt][1][r], h_, l_); sh[lrow*136 + c1] = h_; sl[lrow*136 + c1] = l_;
            }
        }
        __syncthreads();

        // ---- stage D: GRU ----
        f32x4 gr[4][2], gi[4][2], gh[4][2];
        #pragma unroll
        for (int rt = 0; rt < 4; ++rt) {
            gr[rt][0] = (f32x4){0.f,0.f,0.f,0.f};
            gr[rt][1] = (f32x4){0.f,0.f,0.f,0.f};
        }
        #pragma unroll 1
        for (int kc = 0; kc < 4; ++kc) {
            const int kq = kc*32 + kq0;
            const short* pw0 = wih + (size_t)c0*128 + kq;
            const short* pw1 = wih + (size_t)c1*128 + kq;
            const short* pu0 = whh + (size_t)c0*128 + kq;
            const short* pu1 = whh + (size_t)c1*128 + kq;
            bf16x8 w0h=*(const bf16x8*)pw0, w0l=*(const bf16x8*)(pw0+49152);
            bf16x8 w1h=*(const bf16x8*)pw1, w1l=*(const bf16x8*)(pw1+49152);
            bf16x8 u0h=*(const bf16x8*)pu0, u0l=*(const bf16x8*)(pu0+49152);
            bf16x8 u1h=*(const bf16x8*)pu1, u1l=*(const bf16x8*)(pu1+49152);
            #pragma unroll
            for (int rt = 0; rt < 4; ++rt) {
                const size_t ar = (size_t)(base + rt*16 + ml);
                bf16x8 xh = *(const bf16x8*)&sh[(rt*16+ml)*136 + kq];
                bf16x8 xl = *(const bf16x8*)&sl[(rt*16+ml)*136 + kq];
                bf16x8 hh = *(const bf16x8*)(vfch + ar*128 + kq);
                bf16x8 hl = *(const bf16x8*)(vfcl + ar*128 + kq);
                MFMA3(gr[rt][0], xh, xl, w0h, w0l);
                MFMA3(gr[rt][0], hh, hl, u0h, u0l);
                MFMA3(gr[rt][1], xh, xl, w1h, w1l);
                MFMA3(gr[rt][1], hh, hl, u1h, u1l);
            }
        }
        {
            const float br0 = bih[c0] + bhh[c0], br1 = bih[c1] + bhh[c1];
            #pragma unroll
            for (int rt = 0; rt < 4; ++rt) {
                #pragma unroll
                for (int r = 0; r < 4; ++r) {
                    gr[rt][0][r] = sig1(gr[rt][0][r] + br0);
                    gr[rt][1][r] = sig1(gr[rt][1][r] + br1);
                }
            }
        }
        // gate n
        #pragma unroll
        for (int rt = 0; rt < 4; ++rt) {
            gi[rt][0] = (f32x4){0.f,0.f,0.f,0.f};
            gi[rt][1] = (f32x4){0.f,0.f,0.f,0.f};
            gh[rt][0] = (f32x4){0.f,0.f,0.f,0.f};
            gh[rt][1] = (f32x4){0.f,0.f,0.f,0.f};
        }
        #pragma unroll 1
        for (int kc = 0; kc < 4; ++kc) {
            const int kq = kc*32 + kq0;
            const short* pw0 = wih + (size_t)(256 + c0)*128 + kq;
            const short* pw1 = wih + (size_t)(256 + c1)*128 + kq;
            const short* pu0 = whh + (size_t)(256 + c0)*128 + kq;
            const short* pu1 = whh + (size_t)(256 + c1)*128 + kq;
            bf16x8 w0h=*(const bf16x8*)pw0, w0l=*(const bf16x8*)(pw0+49152);
            bf16x8 w1h=*(const bf16x8*)pw1, w1l=*(const bf16x8*)(pw1+49152);
            bf16x8 u0h=*(const bf16x8*)pu0, u0l=*(const bf16x8*)(pu0+49152);
            bf16x8 u1h=*(const bf16x8*)pu1, u1l=*(const bf16x8*)(pu1+49152);
            #pragma unroll
            for (int rt = 0; rt < 4; ++rt) {
                const size_t ar = (size_t)(base + rt*16 + ml);
                bf16x8 xh = *(const bf16x8*)&sh[(rt*16+ml)*136 + kq];
                bf16x8 xl = *(const bf16x8*)&sl[(rt*16+ml)*136 + kq];
                bf16x8 hh = *(const bf16x8*)(vfch + ar*128 + kq);
                bf16x8 hl = *(const bf16x8*)(vfcl + ar*128 + kq);
                MFMA3(gi[rt][0], xh, xl, w0h, w0l);
                MFMA3(gh[rt][0], hh, hl, u0h, u0l);
                MFMA3(gi[rt][1], xh, xl, w1h, w1l);
                MFMA3(gh[rt][1], hh, hl, u1h, u1l);
            }
        }
        {
            const float bn0 = bih[256+c0], bn1 = bih[256+c1];
            const float un0 = bhh[256+c0], un1 = bhh[256+c1];
            #pragma unroll
            for (int rt = 0; rt < 4; ++rt) {
                #pragma unroll
                for (int r = 0; r < 4; ++r) {
                    gi[rt][0][r] = tanhf(gi[rt][0][r] + bn0 + gr[rt][0][r]*(gh[rt][0][r] + un0));
                    gi[rt][1][r] = tanhf(gi[rt][1][r] + bn1 + gr[rt][1][r]*(gh[rt][1][r] + un1));
                }
            }
        }
        // gate z: combined, accumulate into gh (freed)
        #pragma unroll
        for (int rt = 0; rt < 4; ++rt) {
            gh[rt][0] = (f32x4){0.f,0.f,0.f,0.f};
            gh[rt][1] = (f32x4){0.f,0.f,0.f,0.f};
        }
        #pragma unroll 1
        for (int kc = 0; kc < 4; ++kc) {
            const int kq = kc*32 + kq0;
            const short* pw0 = wih + (size_t)(128 + c0)*128 + kq;
            const short* pw1 = wih + (size_t)(128 + c1)*128 + kq;
            const short* pu0 = whh + (size_t)(128 + c0)*128 + kq;
            const short* pu1 = whh + (size_t)(128 + c1)*128 + kq;
            bf16x8 w0h=*(const bf16x8*)pw0, w0l=*(const bf16x8*)(pw0+49152);
            bf16x8 w1h=*(const bf16x8*)pw1, w1l=*(const bf16x8*)(pw1+49152);
            bf16x8 u0h=*(const bf16x8*)pu0, u0l=*(const bf16x8*)(pu0+49152);
            bf16x8 u1h=*(const bf16x8*)pu1, u1l=*(const bf16x8*)(pu1+49152);
            #pragma unroll
            for (int rt = 0; rt < 4; ++rt) {
                const size_t ar = (size_t)(base + rt*16 + ml);
                bf16x8 xh = *(const bf16x8*)&sh[(rt*16+ml)*136 + kq];
                bf16x8 xl = *(const bf16x8*)&sl[(rt*16+ml)*136 + kq];
                bf16x8 hh = *(const bf16x8*)(vfch + ar*128 + kq);
                bf16x8 hl = *(const bf16x8*)(vfcl + ar*128 + kq);
                MFMA3(gh[rt][0], xh, xl, w0h, w0l);
                MFMA3(gh[rt][0], hh, hl, u0h, u0l);
                MFMA3(gh[rt][1], xh, xl, w1h, w1l);
                MFMA3(gh[rt][1], hh, hl, u1h, u1l);
            }
        }
        {
            const float bz0 = bih[128+c0] + bhh[128+c0];
            const float bz1 = bih[128+c1] + bhh[128+c1];
            #pragma unroll
            for (int rt = 0; rt < 4; ++rt) {
                #pragma unroll
                for (int r = 0; r < 4; ++r) {
                    const size_t grow = (size_t)(base + rt*16 + quad*4 + r);
                    const size_t off0 = grow*128 + c0, off1 = grow*128 + c1;
                    float z0 = sig1(gh[rt][0][r] + bz0);
                    float z1 = sig1(gh[rt][1][r] + bz1);
                    float o0 = (1.f-z0)*gi[rt][0][r] + z0*vfc[off0];
                    float o1 = (1.f-z1)*gi[rt][1][r] + z1*vfc[off1];
                    vfn[off0] = o0; vfn[off1] = o1;
                    short h_, l_;
                    split2(o0, h_, l_); vfnh[off0] = h_; vfnl[off0] = l_;
                    split2(o1, h_, l_); vfnh[off1] = h_; vfnl[off1] = l_;
                }
            }
        }
    } else {
        // ---------------- master path (blocks 0..63, overlaps vchain) ------
        float* smemf = (float*)smem_raw;
        float* xs = smemf;            // 512
        float* ms = smemf + 512;      // 128
        float* msN = smemf + 640;     // 128
        float* v_mtm = smemf + 768;   // 128
        float* v_mself = smemf + 896; // 128
        float* v_m2m = smemf + 1024;  // 128
        float* v_t2 = smemf + 1152;   // 128
        float* v_ts1 = smemf + 1280;  // 128
        float* v_ts2 = smemf + 1408;  // 128
        float* v_hsup = smemf + 1536; // 128
        float* gi = smemf + 1664;     // 384
        float* gh2 = smemf + 2048;    // 384
        float* red = smemf + 2432;    // 256
        const int b = bid;

        if (t < 128) ms[t] = master[(size_t)b*128 + t];
        __syncthreads();

        const int c = t & 127, p = t >> 7;

        #pragma unroll
        for (int k = 0; k < 4; ++k) {
            const float* cx = ctx + ((size_t)b*KK + k)*128;
            const float* Wk = wmain_w + (size_t)k*16384;
            float s = 0.f;
            for (int d = p*64; d < p*64+64; ++d) s += cx[d]*Wk[(size_t)d*128 + c];
            red[t] = s; __syncthreads();
            if (t < 128) xs[k*128 + c] = red[c] + red[c+128] + satt[(size_t)b*KK + k]*wmain_b[k*128 + c];
            __syncthreads();
        }

        auto matvec = [&](const float* src, const float* __restrict__ W,
                          const float* __restrict__ bias, int K, float* out, int act) {
            int half = K >> 1;
            int k0 = p*half, k1 = k0 + half;
            float s = 0.f;
            for (int k = k0; k < k1; ++k) s += src[k]*W[(size_t)k*128 + c];
            red[t] = s; __syncthreads();
            if (t < 128) {
                float v = red[c] + red[c+128] + bias[c];
                if (act == 1) v = gelu1(v); else if (act == 2) v = tanhf(v);
                out[c] = v;
            }
            __syncthreads();
        };

        matvec(xs, khead_w, khead_b, 512, v_mtm, 2);
        matvec(ms, wmaster_w, wmaster_b, 128, v_mself, 1);
        matvec(v_mself, wzs1_w, wzs1_b, 128, v_ts1, 0);
        matvec(v_mtm, wzs2_w, wzs2_b, 128, v_ts2, 0);

        if (t < 128) {
            float z = sig1(v_ts1[t] + v_ts2[t]);
            v_hsup[t] = (1.f-z)*v_mself[t] + z*v_mtm[t];
        }
        __syncthreads();

        for (int j = t; j < 384; j += 256) {
            float a = 0.f, h2 = 0.f;
            for (int k = 0; k < 128; ++k) {
                a  += v_hsup[k]*WTih[(size_t)k*384 + j];
                h2 += ms[k]*WThh[(size_t)k*384 + j];
            }
            gi[j] = a + bihm[j];
            gh2[j] = h2 + bhhm[j];
        }
        __syncthreads();
        if (t < 128) {
            float r = sig1(gi[t] + gh2[t]);
            float z = sig1(gi[128+t] + gh2[128+t]);
            float n = tanhf(gi[256+t] + r*gh2[256+t]);
            float nm = (1.f-z)*n + z*ms[t];
            master[(size_t)b*128 + t] = nm;
            msN[t] = nm;
        }
        __syncthreads();

        matvec(msN, wm2m_n_w, wm2m_n_b, 128, v_m2m, 1);
        matvec(v_m2m, wzm2_n_w, wzm2_n_b, 128, v_t2, 0);
        if (t < 128) {
            m2m_out[(size_t)b*128 + t] = v_m2m[t];
            t2_out[(size_t)b*128 + t]  = v_t2[t];
        }
    }
}

// ---------------------------------------------------------------------------
// embed: vf = gelu((atomf[vertex]*vm)@emb + b); stores fp32 vf, planes, bf16 h0
// ---------------------------------------------------------------------------
__global__ __launch_bounds__(256) void embed_kernel(
    const float* __restrict__ atomf, const int* __restrict__ vertex,
    const float* __restrict__ vmask,
    const short* __restrict__ WT, const float* __restrict__ bias,
    float* __restrict__ vf, short* __restrict__ h0b,
    short* __restrict__ vfh, short* __restrict__ vfl)
{
    const int t = threadIdx.x;
    const int lane = t & 63, wv = t >> 6;
    const int quad = lane >> 4, ml = lane & 15;
    const int m0 = blockIdx.x*128 + wv*32;
    const int r0 = m0 + ml, r1 = m0 + 16 + ml;
    const int ga0 = vertex[r0], ga1 = vertex[r1];
    const float vm0 = vmask[r0], vm1 = vmask[r1];

    f32x4 acc[16];
    #pragma unroll
    for (int i = 0; i < 16; ++i) acc[i] = (f32x4){0.f,0.f,0.f,0.f};
    const short* wcol = WT + (size_t)ml*96;

    #pragma unroll
    for (int kc = 0; kc < 3; ++kc) {
        const int kq = kc*32 + quad*8;
        float av0[8], av1[8];
        const float* p0r = atomf + (size_t)ga0*AF + kq;
        const float* p1r = atomf + (size_t)ga1*AF + kq;
        #pragma unroll
        for (int j2 = 0; j2 < 4; ++j2) {
            int k = kq + 2*j2;
            if (k + 2 <= AF) {
                float2 v0 = *(const float2*)(p0r + 2*j2);
                float2 v1 = *(const float2*)(p1r + 2*j2);
                av0[2*j2]=v0.x*vm0; av0[2*j2+1]=v0.y*vm0;
                av1[2*j2]=v1.x*vm1; av1[2*j2+1]=v1.y*vm1;
            } else { av0[2*j2]=0.f; av0[2*j2+1]=0.f; av1[2*j2]=0.f; av1[2*j2+1]=0.f; }
        }
        bf16x8 a0h, a0l, a1h, a1l;
        #pragma unroll
        for (int j = 0; j < 8; ++j) {
            short h, l;
            split2(av0[j], h, l); a0h[j]=h; a0l[j]=l;
            split2(av1[j], h, l); a1h[j]=h; a1l[j]=l;
        }
        #pragma unroll
        for (int nt = 0; nt < 8; ++nt) {
            const short* bp = wcol + (size_t)nt*16*96 + kq;
            bf16x8 bh = *(const bf16x8*)bp;
            bf16x8 bl = *(const bf16x8*)(bp + 12288);
            MFMA3(acc[nt],   a0h, a0l, bh, bl);
            MFMA3(acc[8+nt], a1h, a1l, bh, bl);
        }
    }

    #pragma unroll
    for (int mt = 0; mt < 2; ++mt) {
        #pragma unroll
        for (int nt = 0; nt < 8; ++nt) {
            int col = nt*16 + ml;
            float bj = bias[col];
            #pragma unroll
            for (int r = 0; r < 4; ++r) {
                int gm = m0 + mt*16 + quad*4 + r;
                float v = gelu1(acc[mt*8+nt][r] + bj);
                size_t off = (size_t)gm*128 + col;
                vf[off] = v;
                short h_, l_; split2(v, h_, l_);
                vfh[off] = h_; vfl[off] = l_;
                h0b[off] = h_;
            }
        }
    }
}

// ---------------------------------------------------------------------------
// master_init_a: partial sums (512 blocks) -> atomicAdd into zeroed master
// master_init_b: m2m_0 / t2_0 from master (64 blocks)
// ---------------------------------------------------------------------------
__global__ __launch_bounds__(256) void master_init_a(
    const float* __restrict__ vf, const float* __restrict__ vm,
    float* __restrict__ master)
{
    __shared__ float red[256];
    const int bid = blockIdx.x;
    const int b = bid >> 3, sl = bid & 7;
    const int t = threadIdx.x;
    const int c = t & 127, half = t >> 7;
    float s = 0.f;
    for (int n = sl*64 + half; n < sl*64 + 64; n += 2)
        s += vf[((size_t)b*NN + n)*HH + c] * vm[b*NN + n];
    red[t] = s; __syncthreads();
    if (t < 128) atomicAdd(&master[(size_t)b*HH + c], red[c] + red[c+128]);
}

__global__ __launch_bounds__(256) void master_init_b(
    const float* __restrict__ master,
    const float* __restrict__ wm2m_w, const float* __restrict__ wm2m_b,
    const float* __restrict__ wzm2_w, const float* __restrict__ wzm2_b,
    float* __restrict__ m2m_out, float* __restrict__ t2_out)
{
    __shared__ float red[256], ms[128], v_m2m[128];
    const int b = blockIdx.x, t = threadIdx.x;
    if (t < 128) ms[t] = master[(size_t)b*HH + t];
    __syncthreads();
    const int c = t & 127, p = t >> 7;
    {
        float s2 = 0.f;
        for (int k = p*64; k < p*64+64; ++k) s2 += ms[k]*wm2m_w[(size_t)k*128 + c];
        red[t] = s2; __syncthreads();
        if (t < 128) { float v = gelu1(red[c] + red[c+128] + wm2m_b[c]); v_m2m[c] = v; m2m_out[(size_t)b*128 + c] = v; }
        __syncthreads();
    }
    {
        float s2 = 0.f;
        for (int k = p*64; k < p*64+64; ++k) s2 += v_m2m[k]*wzm2_w[(size_t)k*128 + c];
        red[t] = s2; __syncthreads();
        if (t < 128) t2_out[(size_t)b*128 + c] = red[c] + red[c+128] + wzm2_b[c];
    }
}

// ---------------------------------------------------------------------------
// weight prep: all converts/transposes + pet table + W_BC + zmb2 + master zero
// ---------------------------------------------------------------------------
__device__ __forceinline__ void cvt_t2(const float* __restrict__ src, short* __restrict__ dst,
                                       int i, int K, int Kpad, int total, int zrows)
{
    int z = i / (128*Kpad); int rem = i - z*128*Kpad;
    int col = rem / Kpad; int k = rem - col*Kpad;
    float v = (k < K) ? src[(size_t)z*zrows*128 + (size_t)k*128 + col] : 0.f;
    short h, l; split2(v, h, l);
    dst[i] = h; dst[total + i] = l;
}

__global__ void wprep_kernel(
    const float* __restrict__ emb_w, const float* __restrict__ wvm_w,
    const float* __restrict__ u1_w, const float* __restrict__ u1_b,
    const float* __restrict__ u2_w,
    const float* __restrict__ fu_w, const float* __restrict__ fu_bv,
    const float* __restrict__ wzm1_w, const float* __restrict__ wzm1_bv,
    const float* __restrict__ g_wih, const float* __restrict__ g_whh,
    const float* __restrict__ gm_wih, const float* __restrict__ gm_whh,
    const float* __restrict__ bondf,
    short* __restrict__ wt_emb, short* __restrict__ wt_wvm,
    short* __restrict__ wt_pv, short* __restrict__ wt_u2,
    short* __restrict__ wt_fu, short* __restrict__ wt_wzm1,
    short* __restrict__ wt_gih, short* __restrict__ wt_ghh,
    short* __restrict__ wt_wbc, float* __restrict__ zmb2,
    float* __restrict__ WTih_s, float* __restrict__ WThh_s,
    float* __restrict__ pet, float* __restrict__ master0)
{
    int i = blockIdx.x*256 + threadIdx.x;
    if (i < 12288) cvt_t2(emb_w, wt_emb, i, 82, 96, 12288, 82);
    else if (i < 208896) cvt_t2(wvm_w, wt_wvm, i-12288, 128, 128, 196608, 128);
    else if (i < 258048) cvt_t2(u1_w, wt_pv, i-208896, 128, 128, 49152, 134);
    else if (i < 356352) cvt_t2(u2_w, wt_u2, i-258048, 256, 256, 98304, 256);
    else if (i < 405504) cvt_t2(fu_w, wt_fu, i-356352, 128, 128, 49152, 128);
    else if (i < 454656) cvt_t2(wzm1_w, wt_wzm1, i-405504, 128, 128, 49152, 128);
    else if (i < 503808) { int j = i-454656; short h,l; split2(g_wih[j],h,l); wt_gih[j]=h; wt_gih[49152+j]=l; }
    else if (i < 552960) { int j = i-503808; short h,l; split2(g_whh[j],h,l); wt_ghh[j]=h; wt_ghh[49152+j]=l; }
    else if (i < 602112) { int o = i-552960; int k = o/384, j = o-k*384; WTih_s[o] = gm_wih[j*128 + k]; }
    else if (i < 651264) { int o = i-602112; int k = o/384, j = o-k*384; WThh_s[o] = gm_whh[j*128 + k]; }
    else if (i < 655104) {
        int o = i-651264;               // < 3*10*128
        int l = o / 1280; int rem = o - l*1280;
        int e = rem >> 7; int c = rem & 127;
        float acc = u1_b[l*128 + c];
        #pragma unroll
        for (int j = 0; j < 6; ++j)
            acc += bondf[e*6 + j] * u1_w[((size_t)l*134 + 128 + j)*128 + c];
        pet[o] = acc;
    }
    else if (i < 704256) {
        // W_BC[l][in=k][out=c] = theta*sum_j fu[l][k][j]*wzm1[l][j][c] + (1-theta)*wzm1[l][k][c]
        int o = i - 655104;             // l*16384 + k*128 + c
        int li = o >> 14; int rem = o & 16383;
        int k = rem >> 7; int c = rem & 127;
        float theta = logf(0.5f/(float)(li+1) + 1.f);
        const float* fu = fu_w + (size_t)li*16384 + (size_t)k*128;
        const float* wz = wzm1_w + (size_t)li*16384;
        float s = 0.f;
        for (int j = 0; j < 128; ++j) s += fu[j] * wz[(size_t)j*128 + c];
        s = theta*s + (1.f-theta)*wz[(size_t)k*128 + c];
        short h, lo; split2(s, h, lo);
        size_t d = (size_t)li*16384 + (size_t)c*128 + k;   // transposed [col][k]
        wt_wbc[d] = h; wt_wbc[49152 + d] = lo;
    }
    else if (i < 704640) {
        // zmb2[l][c] = wzm1_b[l][c] + theta*sum_j fu_b[l][j]*wzm1[l][j][c]
        int o = i - 704256; int li = o >> 7; int c = o & 127;
        float theta = logf(0.5f/(float)(li+1) + 1.f);
        float s = 0.f;
        for (int j = 0; j < 128; ++j)
            s += fu_bv[li*128 + j] * wzm1_w[(size_t)li*16384 + (size_t)j*128 + c];
        zmb2[o] = wzm1_bv[li*128 + c] + theta*s;
    }
    else if (i < 712832) {
        master0[i - 704640] = 0.f;      // zero master for atomic partial sums
    }
}

__global__ void copy_out_kernel(const float* __restrict__ vf, const float* __restrict__ master,
                                float* __restrict__ out)
{
    int i = blockIdx.x*256 + threadIdx.x;
    const int nvf4 = SLAB/4;
    if (i < nvf4) ((float4*)out)[i] = ((const float4*)vf)[i];
    else ((float4*)out)[i] = ((const float4*)master)[i - nvf4];
}

// ---------------------------------------------------------------------------
extern "C" void kernel_launch(void* const* d_in, const int* in_sizes, int n_in,
                              void* d_out, int out_size, void* d_ws, size_t ws_size,
                              hipStream_t stream)
{
    (void)in_sizes; (void)n_in; (void)out_size; (void)ws_size;
    const float* vmask = (const float*)d_in[1];
    const int*   vertex= (const int*)d_in[2];
    const int*   edge  = (const int*)d_in[3];
    const int*   aadj  = (const int*)d_in[4];
    const int*   badj  = (const int*)d_in[5];
    const float* nbm   = (const float*)d_in[6];
    const float* atomf = (const float*)d_in[7];
    const float* bondf = (const float*)d_in[8];
    const float* emb_w = (const float*)d_in[9];
    const float* emb_b = (const float*)d_in[10];
    const float* u1_w  = (const float*)d_in[11];
    const float* u1_b  = (const float*)d_in[12];
    const float* u2_w  = (const float*)d_in[13];
    const float* u2_b  = (const float*)d_in[14];
    const float* fu_w  = (const float*)d_in[15];
    const float* fu_b  = (const float*)d_in[16];
    const float* wvm_w = (const float*)d_in[17];
    const float* wvm_b = (const float*)d_in[18];
    const float* wmain_w=(const float*)d_in[19];
    const float* wmain_b=(const float*)d_in[20];
    const float* wbmm_w= (const float*)d_in[21];
    const float* wbmm_b= (const float*)d_in[22];
    const float* khead_w=(const float*)d_in[23];
    const float* khead_b=(const float*)d_in[24];
    const float* wmaster_w=(const float*)d_in[25];
    const float* wmaster_b=(const float*)d_in[26];
    const float* wm2m_w= (const float*)d_in[27];
    const float* wm2m_b= (const float*)d_in[28];
    const float* wzm1_w= (const float*)d_in[29];
    const float* wzm1_b= (const float*)d_in[30];
    const float* wzm2_w= (const float*)d_in[31];
    const float* wzm2_b= (const float*)d_in[32];
    const float* wzs1_w= (const float*)d_in[33];
    const float* wzs1_b= (const float*)d_in[34];
    const float* wzs2_w= (const float*)d_in[35];
    const float* wzs2_b= (const float*)d_in[36];
    const float* g_wih = (const float*)d_in[37];
    const float* g_whh = (const float*)d_in[38];
    const float* g_bih = (const float*)d_in[39];
    const float* g_bhh = (const float*)d_in[40];
    const float* gm_wih= (const float*)d_in[41];
    const float* gm_whh= (const float*)d_in[42];
    const float* gm_bih= (const float*)d_in[43];
    const float* gm_bhh= (const float*)d_in[44];

    float* ws     = (float*)d_ws;
    float* vfA    = ws;
    float* vfB    = vfA + SLAB;
    float* score  = vfB + SLAB;
    float* ctx    = score + BB*KK*NN;
    float* satt   = ctx + BB*KK*HH;
    float* master = satt + BB*KK;
    float* m2mA   = master + BB*HH;
    float* t2A    = m2mA + BB*HH;
    float* m2mB   = t2A + BB*HH;
    float* t2B    = m2mB + BB*HH;
    float* WTih_s = t2B + BB*HH;
    float* WThh_s = WTih_s + 128*384;
    float* pet    = WThh_s + 128*384;       // 3*10*128
    short* vfhA   = (short*)(pet + 3840);
    short* vflA   = vfhA + SLAB;
    short* vfhB   = vflA + SLAB;
    short* vflB   = vfhB + SLAB;
    short* nlh    = vflB + SLAB;
    short* nll    = nlh + SLAB;
    short* pvfb   = nll + SLAB;
    short* h0b    = pvfb + SLAB;
    short* wt_emb   = h0b + SLAB;
    short* wt_wvm   = wt_emb   + 2*12288;
    short* wt_pv    = wt_wvm   + 2*196608;
    short* wt_u2    = wt_pv    + 2*49152;
    short* wt_fu    = wt_u2    + 2*98304;
    short* wt_wzm1  = wt_fu    + 2*49152;
    short* wt_gih   = wt_wzm1  + 2*49152;
    short* wt_ghh   = wt_gih   + 2*49152;
    short* wt_wbc   = wt_ghh   + 2*49152;
    float* zmb2     = (float*)(wt_wbc + 2*49152);  // 3*128

    wprep_kernel<<<2785, 256, 0, stream>>>(
        emb_w, wvm_w, u1_w, u1_b, u2_w, fu_w, fu_b, wzm1_w, wzm1_b,
        g_wih, g_whh, gm_wih, gm_whh, bondf,
        wt_emb, wt_wvm, wt_pv, wt_u2, wt_fu, wt_wzm1, wt_gih, wt_ghh,
        wt_wbc, zmb2, WTih_s, WThh_s, pet, master);

    embed_kernel<<<256, 256, 0, stream>>>(atomf, vertex, vmask, wt_emb, emb_b,
                                          vfA, h0b, vfhA, vflA);

    master_init_a<<<512, 256, 0, stream>>>(vfA, vmask, master);
    master_init_b<<<BB, 256, 0, stream>>>(master, wm2m_w, wm2m_b, wzm2_w, wzm2_b,
                                          m2mA, t2A);

    for (int i = 0; i < LL; ++i) {
        float theta = logf(0.5f/(float)(i+1) + 1.f);
        const bool even = (i % 2 == 0);
        float* vfc  = even ? vfA  : vfB;
        short* vfch = even ? vfhA : vfhB;
        short* vfcl = even ? vflA : vflB;
        float* vfn  = even ? vfB  : vfA;
        short* vfnh = even ? vfhB : vfhA;
        short* vfnl = even ? vflB : vflA;
        // t2/m2m double-buffer: read current, master path writes next
        float* m2mR = even ? m2mA : m2mB;
        float* t2R  = even ? t2A  : t2B;
        float* m2mW = even ? m2mB : m2mA;
        float* t2W  = even ? t2B  : t2A;
        int nx = (i+1 < LL) ? i+1 : i;

        layer_k1<<<1280, 256, 0, stream>>>(
            vfch, vfcl,
            wt_pv + (size_t)i*16384, pvfb,
            wt_wvm + (size_t)i*4*16384, wvm_b + (size_t)i*4*128,
            master, wbmm_w + (size_t)i*KK*HH, wbmm_b + (size_t)i*KK, score);

        layer_k2<<<8448, 256, 0, stream>>>(
            pvfb, pet + (size_t)i*1280,
            aadj, badj, edge, nbm, nlh, nll,
            score, vmask, vfc, satt, ctx);

        layer_k3<<<576, 256, 0, stream>>>(
            nlh, nll, vfc, vfch, vfcl, vfn, vfnh, vfnl, h0b,
            wt_u2 + (size_t)i*128*256, u2_b + i*HH,
            wt_fu + (size_t)i*16384, fu_b + i*HH,
            wt_wbc + (size_t)i*16384, zmb2 + i*HH,
            wt_gih, wt_ghh, g_bih, g_bhh,
            t2R, m2mR, theta,
            ctx, satt, master,
            wmain_w + (size_t)i*KK*HH*HH, wmain_b + (size_t)i*KK*HH,
            khead_w + (size_t)i*KK*HH*HH, khead_b + i*HH,
            wmaster_w + (size_t)i*HH*HH, wmaster_b + i*HH,
            wzs1_w + (size_t)i*HH*HH, wzs1_b + i*HH,
            wzs2_w + (size_t)i*HH*HH, wzs2_b + i*HH,
            WTih_s, WThh_s, gm_bih, gm_bhh,
            wm2m_w + (size_t)nx*HH*HH, wm2m_b + nx*HH,
            wzm2_w + (size_t)nx*HH*HH, wzm2_b + nx*HH,
            m2mW, t2W);
    }

    copy_out_kernel<<<(SLAB + BB*HH)/4/256, 256, 0, stream>>>(vfB, master, (float*)d_out);
}